// Round 11
// baseline (719.073 us; speedup 1.0000x reference)
//
#include <hip/hip_runtime.h>
#include <hip/hip_bf16.h>
#include <cmath>

#define S_LEN 2048
#define E_DIM 512
#define B_SZ 4
#define CIN_D 64
#define COUT_D 64
#define L_NUM 4
#define CHK 256
#define NCHK 8
#define ROWS (B_SZ * S_LEN)  // 8192
#define PADR 2050            // padded rows per batch for causal conv
#define QLD 1024             // leading dim of fused qk buffer

typedef __attribute__((ext_vector_type(8))) short short8;
typedef __attribute__((ext_vector_type(4))) float f32x4;
typedef unsigned short ushort_t;

__device__ __forceinline__ ushort_t f2b(float v) {
  __hip_bfloat16 t = __float2bfloat16(v);
  return __builtin_bit_cast(ushort_t, t);
}
__device__ __forceinline__ float b2f(ushort_t u) {
  return __builtin_bit_cast(float, ((unsigned)u) << 16);
}
__device__ __forceinline__ float b2f(unsigned u) {
  return __builtin_bit_cast(float, u << 16);
}

__device__ __forceinline__ void gload16(const void* g, void* l) {
  __builtin_amdgcn_global_load_lds((const __attribute__((address_space(1))) void*)g,
                                   (__attribute__((address_space(3))) void*)l, 16, 0, 0);
}

__device__ __forceinline__ void barrier_mem() {
  asm volatile("s_barrier" ::: "memory");
}
template <int N>
__device__ __forceinline__ void waitn() {
  if constexpr (N == 0) asm volatile("s_waitcnt vmcnt(0)" ::: "memory");
  else if constexpr (N == 6) asm volatile("s_waitcnt vmcnt(6)" ::: "memory");
  else asm volatile("s_waitcnt vmcnt(8)" ::: "memory");
  __builtin_amdgcn_sched_barrier(0);
}

// ======================= universal bf16 MFMA GEMM =======================
struct GemmP {
  const ushort_t* A; const ushort_t* B; const float* bias;
  ushort_t* Cb; const float* den;
  int nkt, lda, ldb, ldc;
  int aZrow, aZcol, bZrow, bZcol, cZrow;
  const ushort_t* A2; const ushort_t* B2;
  int nkt2, lda2, ldb2, a2Zrow, b2Zrow;
  // LN fusion: sin_ = per-row stats in (8 slots x (S,Q)); sout_ = stats out;
  // cg/dv = precomputed rowsum(W*g) and bb@W^T + bias vectors.
  const float* sin_; float* sout_; const float* cg; const float* dv;
};

template <int TM, int TN, bool CONV>
__device__ __forceinline__ void mma_phase(const ushort_t* A, const ushort_t* B,
                                          int nkt, int lda, int ldb, int arow0,
                                          int acol0, int brow0, int bcol0,
                                          char* sm, int tid,
                                          f32x4 (&acc)[TM / 32][TN / 32]) {
  constexpr int MF = TM / 32, NF = TN / 32;
  constexpr int ABY = TM * 128, BBY = TN * 128, BUF = ABY + BBY;
  constexpr int RA = ABY / 4096, RB = BBY / 4096;
  const int lane = tid & 63, w = tid >> 6;
  const int wr = (w >> 1) * (TM / 2), wc = (w & 1) * (TN / 2);
  const int l15 = lane & 15, l4 = lane >> 4;

  auto stage = [&](int kt, int buf) {
    int ar0 = arow0, ac0 = acol0 + (kt << 6);
    if (CONV) {
      ar0 = arow0 + (kt >> 3);
      ac0 = acol0 + ((kt & 7) << 6);
    }
    char* s = sm + buf * BUF;
#pragma unroll
    for (int r = 0; r < RA; ++r) {
      const int f = (r << 12) + (tid << 4);
      const int row = f >> 7, sw = ((((f >> 4) & 7)) ^ (row & 7)) << 3;
      gload16(A + (size_t)(ar0 + row) * lda + ac0 + sw, s + f);
    }
    const int bc0 = bcol0 + (kt << 6);
#pragma unroll
    for (int r = 0; r < RB; ++r) {
      const int f = (r << 12) + (tid << 4);
      const int row = f >> 7, sw = ((((f >> 4) & 7)) ^ (row & 7)) << 3;
      gload16(B + (size_t)(brow0 + row) * ldb + bc0 + sw, s + ABY + f);
    }
  };

  stage(0, 0);
  int cur = 0;
  for (int kt = 0; kt < nkt; ++kt) {
    if (kt + 1 < nkt) {
      stage(kt + 1, cur ^ 1);  // prefetch next tile
      waitn<RA + RB>();        // wait ONLY the older (current) tile
    } else {
      waitn<0>();
    }
    barrier_mem();
    char* s = sm + cur * BUF;
#pragma unroll
    for (int kk = 0; kk < 2; ++kk) {
      short8 af[MF], bfv[NF];
#pragma unroll
      for (int m = 0; m < MF; ++m) {
        const int rt = wr + (m << 4) + l15;
        af[m] = *(const short8*)(s + rt * 128 +
                                 (((kk << 6) + (l4 << 4)) ^ ((rt & 7) << 4)));
      }
#pragma unroll
      for (int n = 0; n < NF; ++n) {
        const int rt = wc + (n << 4) + l15;
        bfv[n] = *(const short8*)(s + ABY + rt * 128 +
                                  (((kk << 6) + (l4 << 4)) ^ ((rt & 7) << 4)));
      }
#pragma unroll
      for (int m = 0; m < MF; ++m)
#pragma unroll
        for (int n = 0; n < NF; ++n)
          acc[m][n] = __builtin_amdgcn_mfma_f32_16x16x32_bf16(af[m], bfv[n],
                                                              acc[m][n], 0, 0, 0);
    }
    __builtin_amdgcn_sched_barrier(0);
    asm volatile("s_waitcnt lgkmcnt(0)" ::: "memory");
    barrier_mem();
    cur ^= 1;
  }
}

// ACT: 0 none, 1 phi, 2 gelu, 3 phi-if-row<512 (fused k|v)
// LNM: 0 none, 1 = A-side LN fusion (per-row stats), 2 = B-side (per-col)
template <int TM, int TN, int ACT, bool READC, bool PADA, bool PADC,
          bool BIASROW, bool TRIMASK, bool SKIPUP, bool DIVDEN, bool TWOPH,
          bool CONV, bool HALFK, int LNM, bool SOUT>
__device__ __forceinline__ void gemm_body(const GemmP& p, int bm, int bn,
                                          int z, int tid, char* smem) {
  constexpr int MF = TM / 32, NF = TN / 32;
  const int lane = tid & 63, w = tid >> 6;
  const int wr = (w >> 1) * (TM / 2), wc = (w & 1) * (TN / 2);
  const int l15 = lane & 15, l4 = lane >> 4;

  if (SKIPUP && bn >= bm + TM) {  // fully-masked tile: zero-fill Cb
#pragma unroll
    for (int m = 0; m < MF; ++m)
#pragma unroll
      for (int j = 0; j < 4; ++j) {
        const int rloc = bm + wr + (m << 4) + (l4 << 2) + j;
        const size_t crow = (size_t)p.cZrow * z + rloc;
#pragma unroll
        for (int n = 0; n < NF; ++n)
          p.Cb[crow * p.ldc + bn + wc + (n << 4) + l15] = 0;
      }
    return;
  }

  f32x4 acc[MF][NF];
#pragma unroll
  for (int m = 0; m < MF; ++m)
#pragma unroll
    for (int n = 0; n < NF; ++n)
#pragma unroll
      for (int j = 0; j < 4; ++j) acc[m][n][j] = 0.f;

  int arow0 = bm + p.aZrow * z;
  if (PADA) arow0 = bm + ((bm >> 11) << 1);  // padded batch base
  int nkt1 = p.nkt;
  if (HALFK) nkt1 = min(p.nkt, (bm + TM) >> 6);  // causal K truncation
  mma_phase<TM, TN, CONV>(p.A, p.B, nkt1, p.lda, p.ldb, arow0, p.aZcol * z,
                          bn + p.bZrow * z, p.bZcol * z, smem, tid, acc);
  if (TWOPH)
    mma_phase<TM, TN, false>(p.A2, p.B2, p.nkt2, p.lda2, p.ldb2,
                             bm + p.a2Zrow * z, 0, bn + p.b2Zrow * z, 0, smem,
                             tid, acc);

  float bcol[NF];
  if (p.bias && !BIASROW) {
#pragma unroll
    for (int n = 0; n < NF; ++n) bcol[n] = p.bias[bn + wc + (n << 4) + l15];
  }
  float rn[NF], rmn[NF];
  if (LNM == 2) {
#pragma unroll
    for (int n = 0; n < NF; ++n) {
      const int col = bn + wc + (n << 4) + l15;
      const float* sp_ = p.sin_ + ((size_t)col << 4);
      float S = 0.f, Q = 0.f;
#pragma unroll
      for (int t = 0; t < 4; ++t) {
        const float4 s4 = *(const float4*)(sp_ + (t << 2));
        S += s4.x + s4.z;
        Q += s4.y + s4.w;
      }
      const float mm = S * (1.f / 512.f);
      rn[n] = rsqrtf(Q * (1.f / 512.f) - mm * mm + 1e-5f);
      rmn[n] = rn[n] * mm;
    }
  }
  int crow_base = bm;
  if (PADC) crow_base = bm + ((bm >> 11) << 1) + 2;
#pragma unroll
  for (int m = 0; m < MF; ++m) {
#pragma unroll
    for (int j = 0; j < 4; ++j) {
      const int rloc = wr + (m << 4) + (l4 << 2) + j;
      const size_t crow = (size_t)p.cZrow * z + crow_base + rloc;
      float inv = 1.f;
      if (DIVDEN) inv = 1.f / (p.den[crow] + 1e-6f);
      float brbias = 0.f;
      if (BIASROW && p.bias) brbias = p.bias[bm + rloc];
      float r_ = 1.f, rm_ = 0.f;
      if (LNM == 1) {
        const float* sp_ = p.sin_ + (crow << 4);
        float S = 0.f, Q = 0.f;
#pragma unroll
        for (int t = 0; t < 4; ++t) {
          const float4 s4 = *(const float4*)(sp_ + (t << 2));
          S += s4.x + s4.z;
          Q += s4.y + s4.w;
        }
        const float mm = S * (1.f / 512.f);
        r_ = rsqrtf(Q * (1.f / 512.f) - mm * mm + 1e-5f);
        rm_ = r_ * mm;
      }
      float cgr = 0.f, dvr = 0.f;
      if (LNM == 2) {
        cgr = p.cg[bm + rloc];
        dvr = p.dv[bm + rloc];
      }
      float sp = 0.f, qp = 0.f;
#pragma unroll
      for (int n = 0; n < NF; ++n) {
        const int col = bn + wc + (n << 4) + l15;
        float v = acc[m][n][j];
        if (LNM == 1) v = r_ * v - rm_ * p.cg[col] + p.dv[col];
        else if (LNM == 2) v = rn[n] * v - rmn[n] * cgr + dvr;
        else if (p.bias) v += BIASROW ? brbias : bcol[n];
        if (ACT == 1) v = v > 0.f ? v + 1.f : __expf(v);
        if (ACT == 2) v = 0.5f * v * (1.f + erff(v * 0.70710678118654752f));
        if (ACT == 3 && (bm + rloc) < 512) v = v > 0.f ? v + 1.f : __expf(v);
        if (TRIMASK) {
          if (col > bm + rloc) v = 0.f;
        }
        const size_t cidx = crow * p.ldc + col;
        if (READC) v += b2f(p.Cb[cidx]);
        if (DIVDEN) v *= inv;
        const ushort_t uv = f2b(v);
        p.Cb[cidx] = uv;
        if (SOUT) {
          const float vv = b2f(uv);
          sp += vv;
          qp += vv * vv;
        }
      }
      if (SOUT) {
#pragma unroll
        for (int off = 1; off < 16; off <<= 1) {
          sp += __shfl_xor(sp, off);
          qp += __shfl_xor(qp, off);
        }
        if (l15 == 0) {
          const int slot = (bn + wc) >> 6;
          float* so = p.sout_ + (crow << 4) + (slot << 1);
          so[0] = sp;
          so[1] = qp;
        }
      }
    }
  }
}

__device__ __forceinline__ void swz_decode(int r, int gx, int gy, int swz,
                                           int& bx, int& by) {
  if (swz) {
    const int per = gx * gy, cpx = per >> 3;
    const int s = (r & 7) * cpx + (r >> 3);
    if (gx >= gy) { bx = s / gy; by = s % gy; }
    else          { by = s / gx; bx = s % gx; }
  } else {
    bx = r % gx;
    by = r / gx;
  }
}

template <int TM, int TN, int ACT, bool READC, bool PADA, bool PADC,
          bool BIASROW, bool TRIMASK, bool SKIPUP, bool DIVDEN, bool TWOPH,
          bool CONV, bool SWZ, bool HALFK, int LNM, bool SOUT>
__global__ __launch_bounds__(256) void gemm_mfma(GemmP p) {
  __shared__ __align__(16) char smem[2 * (TM + TN) * 128];
  int bxx = blockIdx.x, byy = blockIdx.y;
  if (SWZ) {
    const int gx = gridDim.x, gy = gridDim.y;
    swz_decode(byy * gx + bxx, gx, gy, 1, bxx, byy);
  }
  gemm_body<TM, TN, ACT, READC, PADA, PADC, BIASROW, TRIMASK, SKIPUP, DIVDEN,
            TWOPH, CONV, HALFK, LNM, SOUT>(p, bxx * TM, byy * TN, blockIdx.z,
                                           threadIdx.x, smem);
}

// ======================= small phase bodies =======================

__device__ __forceinline__ void ksum_body(const ushort_t* __restrict__ kT,
                                          float* __restrict__ ks, int unit,
                                          int nunits, int tid) {
  const int wid = tid >> 6, lane = tid & 63;
  const int nw = nunits << 2;
  for (int it = (unit << 2) + wid; it < B_SZ * 7 * E_DIM; it += nw) {
    const int zi = it >> 9, e = it & 511;
    const int z = ((zi / 7) << 3) + zi % 7;
    const uint2 u =
        *(const uint2*)(kT + (size_t)e * ROWS + (z << 8) + (lane << 2));
    float s = b2f(u.x & 0xffffu) + b2f(u.x >> 16) + b2f(u.y & 0xffffu) +
              b2f(u.y >> 16);
#pragma unroll
    for (int off = 32; off; off >>= 1) s += __shfl_xor(s, off);
    if (lane == 0) ks[(z << 9) + e] = s;
  }
}

// ============ mega kernels: template-specialized multi-GEMM launches ========

// qk (128x128, phi, LNM=A) || kvT (128x128, phi-rows<512, LNM=B)
__global__ __launch_bounds__(256) void mega_qkv(GemmP pa, GemmP pb) {
  __shared__ __align__(16) char smem[65536];
  const int tid = threadIdx.x;
  const int bid = blockIdx.x;
  if (bid < 512) {
    int bx, by;
    swz_decode(bid, 64, 8, 1, bx, by);
    gemm_body<128, 128, 1, 0, 0, 0, 0, 0, 0, 0, 0, 0, 0, 1, 0>(
        pa, bx << 7, by << 7, 0, tid, smem);
  } else {
    int bx, by;
    swz_decode(bid - 512, 8, 64, 1, bx, by);
    gemm_body<128, 128, 3, 0, 0, 0, 0, 0, 0, 0, 0, 0, 0, 2, 0>(
        pb, bx << 7, by << 7, 0, tid, smem);
  }
}

// P (128x128, z in 28 chunks) || Sc (128x64, TRIMASK+SKIPUP) || ksum tail
__global__ __launch_bounds__(256) void mega_psck(GemmP pp, GemmP ps,
                                                 const ushort_t* kT,
                                                 float* ks) {
  __shared__ __align__(16) char smem[65536];
  const int tid = threadIdx.x;
  const int bid = blockIdx.x;
  if (bid < 448) {  // P-GEMM, chunk-7 skipped
    int z = bid >> 4;
    z = (z / 7) * 8 + z % 7;
    const int r = bid & 15;
    gemm_body<128, 128, 0, 0, 0, 0, 0, 0, 0, 0, 0, 0, 0, 0, 0>(
        pp, (r & 3) << 7, (r >> 2) << 7, z, tid, smem);
  } else if (bid < 704) {  // intra-chunk scores
    const int v = bid - 448;
    const int z = v >> 3, r = v & 7;
    gemm_body<128, 64, 0, 0, 0, 0, 0, 1, 1, 0, 0, 0, 0, 0, 0>(
        ps, (r & 1) << 7, (r >> 1) << 6, z, tid, smem);
  } else {
    ksum_body(kT, ks, bid - 704, 256, tid);
  }
}

// ======================= prep / small kernels =======================

struct CvtP {
  const float *in_W, *cc_W, *Wq, *Wk, *Wv, *Wo, *c1W, *c2W;
  const float *bq, *bk, *bv, *c1b;
  const float *g1, *b1, *g2, *b2;
  ushort_t *winb, *wconv, *wqkb, *wkvb, *wob, *wc1, *wc2;
  float *cgq, *dq, *cgkv, *dkv, *cg1, *d1;
  ushort_t* t2pad;
};
__global__ void cvt_all(CvtP c) {
  const size_t NT = 32768 + 786432 + 2097152 + 2097152 + 1048576 + 1048576 +
                    1048576 + 4096 + 10240;
  for (size_t i = (size_t)blockIdx.x * 256 + threadIdx.x; i < NT;
       i += (size_t)gridDim.x * 256) {
    size_t j = i;
    if (j < 32768) { c.winb[j] = f2b(c.in_W[j]); continue; }
    j -= 32768;
    if (j < 786432) {
      size_t n = j / 1536, r = j % 1536;
      c.wconv[j] = f2b(c.cc_W[n * 1536 + (r & 511) * 3 + (r >> 9)]);
      continue;
    }
    j -= 786432;
    if (j < 2097152) {  // wqkb = [Wq;Wk] * g1 (LN gain folded)
      size_t l = j >> 19, r = j & 524287, row = r >> 9, k = r & 511;
      float wv = row < 512 ? c.Wq[l * 262144 + row * 512 + k]
                           : c.Wk[l * 262144 + (row - 512) * 512 + k];
      c.wqkb[j] = f2b(wv * c.g1[l * 512 + k]);
      continue;
    }
    j -= 2097152;
    if (j < 2097152) {  // wkvb = [Wk;Wv] * g1
      size_t l = j >> 19, r = j & 524287, row = r >> 9, k = r & 511;
      float wv = row < 512 ? c.Wk[l * 262144 + row * 512 + k]
                           : c.Wv[l * 262144 + (row - 512) * 512 + k];
      c.wkvb[j] = f2b(wv * c.g1[l * 512 + k]);
      continue;
    }
    j -= 2097152;
    if (j < 1048576) { c.wob[j] = f2b(c.Wo[j]); continue; }
    j -= 1048576;
    if (j < 1048576) {  // wc1 = c1W * g2
      size_t l = j >> 18, k = j & 511;
      c.wc1[j] = f2b(c.c1W[j] * c.g2[l * 512 + k]);
      continue;
    }
    j -= 1048576;
    if (j < 1048576) { c.wc2[j] = f2b(c.c2W[j]); continue; }
    j -= 1048576;
    if (j < 4096) {  // zero pad rows of t2pad
      int b = (int)(j >> 10), r = (int)(j & 1023);
      c.t2pad[(size_t)(b * PADR) * E_DIM + r] = 0;
      continue;
    }
    j -= 4096;
    {  // LN-fusion precompute: cg = W.g dot, dv = W.bb dot + bias
      const int unit = (int)j;  // < 10240
      const float *wrow, *gv, *bbv;
      float *cgp, *dvp;
      float bias;
      if (unit < 4096) {
        const int l = unit >> 10, n = unit & 1023;
        wrow = n < 512 ? c.Wq + (size_t)l * 262144 + (size_t)n * 512
                       : c.Wk + (size_t)l * 262144 + (size_t)(n - 512) * 512;
        gv = c.g1 + l * 512; bbv = c.b1 + l * 512;
        bias = n < 512 ? c.bq[l * 512 + n] : c.bk[l * 512 + n - 512];
        cgp = c.cgq + unit; dvp = c.dq + unit;
      } else if (unit < 8192) {
        const int u2 = unit - 4096;
        const int l = u2 >> 10, n = u2 & 1023;
        wrow = n < 512 ? c.Wk + (size_t)l * 262144 + (size_t)n * 512
                       : c.Wv + (size_t)l * 262144 + (size_t)(n - 512) * 512;
        gv = c.g1 + l * 512; bbv = c.b1 + l * 512;
        bias = n < 512 ? c.bk[l * 512 + n] : c.bv[l * 512 + n - 512];
        cgp = c.cgkv + u2; dvp = c.dkv + u2;
      } else {
        const int u2 = unit - 8192;
        const int l = u2 >> 9, n = u2 & 511;
        wrow = c.c1W + (size_t)l * 262144 + (size_t)n * 512;
        gv = c.g2 + l * 512; bbv = c.b2 + l * 512;
        bias = c.c1b[l * 512 + n];
        cgp = c.cg1 + u2; dvp = c.d1 + u2;
      }
      float s1 = 0.f, s2 = 0.f;
      for (int k = 0; k < 512; k += 4) {
        const float4 w4 = *(const float4*)(wrow + k);
        const float4 g4 = *(const float4*)(gv + k);
        const float4 b4 = *(const float4*)(bbv + k);
        s1 += w4.x * g4.x + w4.y * g4.y + w4.z * g4.z + w4.w * g4.w;
        s2 += w4.x * b4.x + w4.y * b4.y + w4.z * b4.z + w4.w * b4.w;
      }
      *cgp = s1;
      *dvp = s2 + bias;
    }
  }
}

__global__ __launch_bounds__(256) void transpose_x(const float* __restrict__ x,
                                                   ushort_t* __restrict__ xT) {
  __shared__ float t[64][65];
  const int b = blockIdx.z, s0 = blockIdx.x << 6, tid = threadIdx.x;
#pragma unroll
  for (int i = 0; i < 16; ++i) {
    int idx = tid + (i << 8);
    int c = idx >> 6, s = idx & 63;
    t[c][s] = x[(((size_t)(b * CIN_D + c)) << 11) + s0 + s];
  }
  __syncthreads();
#pragma unroll
  for (int i = 0; i < 16; ++i) {
    int idx = tid + (i << 8);
    int s = idx >> 6, c = idx & 63;
    xT[(((size_t)(b * S_LEN + s0 + s)) << 6) + c] = f2b(t[c][s]);
  }
}

// merged: blocks 0..4095 = exclusive chunk prefix Pb->PTb (bf16, fp32 acc;
//         chunk-7 Pb never computed -> skipped);
//         blocks 4096..6143 = den (wave per row, ks prefix inlined)
__global__ __launch_bounds__(256) void misc_k(
    const ushort_t* __restrict__ Pb, ushort_t* __restrict__ PTb,
    const ushort_t* __restrict__ Sc, const ushort_t* __restrict__ qk,
    const float* __restrict__ ksum, float* __restrict__ den) {
  int bid = blockIdx.x;
  if (bid < 4096) {
    const size_t idx = ((size_t)bid << 8) + threadIdx.x;  // < B*E*E
    const int b = (int)(idx >> 18);
    const size_t r = idx & ((1u << 18) - 1);
    float acc = 0.f;
#pragma unroll
    for (int j = 0; j < NCHK; ++j) {
      const size_t o = (((size_t)(b * NCHK + j)) << 18) + r;
      PTb[o] = f2b(acc);
      if (j < NCHK - 1) acc += b2f(Pb[o]);
    }
  } else {
    bid -= 4096;
    const int wid = threadIdx.x >> 6, lane = threadIdx.x & 63;
    const int row = (bid << 2) + wid;  // < 8192
    const int z = row >> 8, sl = row & 255;
    const ushort_t* sr = Sc + (((size_t)z) << 16) + ((size_t)sl << 8);
    float s = 0.f;
#pragma unroll
    for (int t = 0; t < 4; ++t) s += b2f(sr[lane + (t << 6)]);
    const ushort_t* qr = qk + (size_t)row * QLD;
    const int j0 = z & ~7;
    for (int e = lane; e < E_DIM; e += 64) {
      float kp = 0.f;
      for (int j = j0; j < z; ++j) kp += ksum[(j << 9) + e];
      s += b2f(qr[e]) * kp;
    }
#pragma unroll
    for (int off = 32; off; off >>= 1) s += __shfl_xor(s, off);
    if (lane == 0) den[row] = s;
  }
}

__global__ __launch_bounds__(256) void out_proj(const ushort_t* __restrict__ lat,
                                                const float* __restrict__ W,
                                                const float* __restrict__ bias,
                                                float* __restrict__ out) {
  const int b = blockIdx.z, bs = blockIdx.x << 6;
  const int tid = threadIdx.x, tm = tid >> 4, tn = tid & 15;
  const int lr = tid >> 2, lc = (tid & 3) << 2;
  __shared__ float As[16][64], Ws[16][64];
  float acc[4][4] = {{0.f}};
  for (int k0 = 0; k0 < E_DIM; k0 += 16) {
    const uint2 ra =
        *(const uint2*)(lat + (((size_t)(b * S_LEN + bs + lr)) << 9) + k0 + lc);
    As[lc + 0][lr] = b2f(ra.x & 0xffffu);
    As[lc + 1][lr] = b2f(ra.x >> 16);
    As[lc + 2][lr] = b2f(ra.y & 0xffffu);
    As[lc + 3][lr] = b2f(ra.y >> 16);
    float4 wv = *(const float4*)(W + (((size_t)lr) << 9) + k0 + lc);
    Ws[lc + 0][lr] = wv.x; Ws[lc + 1][lr] = wv.y;
    Ws[lc + 2][lr] = wv.z; Ws[lc + 3][lr] = wv.w;
    __syncthreads();
#pragma unroll
    for (int kk = 0; kk < 16; ++kk) {
      const float4 a4 = *(const float4*)&As[kk][tm << 2];
      const float4 b4 = *(const float4*)&Ws[kk][tn << 2];
      const float aa[4] = {a4.x, a4.y, a4.z, a4.w};
      const float bb[4] = {b4.x, b4.y, b4.z, b4.w};
#pragma unroll
      for (int i = 0; i < 4; ++i)
#pragma unroll
        for (int j2 = 0; j2 < 4; ++j2) acc[i][j2] += aa[i] * bb[j2];
    }
    __syncthreads();
  }
#pragma unroll
  for (int i = 0; i < 4; ++i)
#pragma unroll
    for (int j2 = 0; j2 < 4; ++j2) {
      const int o = (tn << 2) + j2, sl = bs + (tm << 2) + i;
      out[(((size_t)(b * COUT_D + o)) << 11) + sl] = acc[i][j2] + bias[o];
    }
}

// ======================= host launcher =======================
extern "C" void kernel_launch(void* const* d_in, const int* in_sizes, int n_in,
                              void* d_out, int out_size, void* d_ws,
                              size_t ws_size, hipStream_t stream) {
  const float* x = (const float*)d_in[0];
  const float* in_W = (const float*)d_in[1];
  const float* in_b = (const float*)d_in[2];
  const float* cc_W = (const float*)d_in[3];
  const float* cc_b = (const float*)d_in[4];
  const float* ln1g = (const float*)d_in[5];
  const float* ln1b = (const float*)d_in[6];
  const float* ln2g = (const float*)d_in[7];
  const float* ln2b = (const float*)d_in[8];
  const float* Wq = (const float*)d_in[9];
  const float* bq = (const float*)d_in[10];
  const float* Wk = (const float*)d_in[11];
  const float* bk = (const float*)d_in[12];
  const float* Wv = (const float*)d_in[13];
  const float* bv = (const float*)d_in[14];
  const float* Wo = (const float*)d_in[15];
  const float* bo = (const float*)d_in[16];
  const float* c1W = (const float*)d_in[17];
  const float* c1b = (const float*)d_in[18];
  const float* c2W = (const float*)d_in[19];
  const float* c2b = (const float*)d_in[20];
  const float* oW = (const float*)d_in[21];
  const float* ob = (const float*)d_in[22];
  float* out = (float*)d_out;

  const size_t NE = (size_t)ROWS * E_DIM;  // 4194304
  float* ks = (float*)d_ws;      // 16384
  float* den = ks + 16384;       // 8192
  float* stats1 = den + 8192;    // 8192*16 = 131072
  float* stats2 = stats1 + 131072;  // 131072
  float* cgq = stats2 + 131072;  // 4096
  float* dq = cgq + 4096;        // 4096
  float* cgkv = dq + 4096;       // 4096
  float* dkv = cgkv + 4096;      // 4096
  float* cg1 = dkv + 4096;       // 2048
  float* d1 = cg1 + 2048;        // 2048
  ushort_t* u = (ushort_t*)(d1 + 2048);
  ushort_t* latb = u;   u += NE;
  ushort_t* Pb = u;     u += 8388608;
  ushort_t* xT = u;     u += (size_t)ROWS * CIN_D;
  ushort_t* t2pad = u;  u += (size_t)B_SZ * PADR * E_DIM;
  ushort_t* qk = u;     u += (size_t)ROWS * QLD;
  ushort_t* kvT = u;    u += (size_t)1024 * ROWS;
  ushort_t* PTb = u;    u += 8388608;
  ushort_t* t2b = u;    u += NE;
  ushort_t* winb = u;   u += 32768;
  ushort_t* wconv = u;  u += 786432;
  ushort_t* wqkb = u;   u += 2097152;
  ushort_t* wkvb = u;   u += 2097152;
  ushort_t* wob = u;    u += 1048576;
  ushort_t* wc1 = u;    u += 1048576;
  ushort_t* wc2 = u;    u += 1048576;
  ushort_t* Sc = t2pad;  // alias: t2pad dead after conv
  ushort_t* kT = kvT;
  ushort_t* vT = kvT + (size_t)512 * ROWS;

  const dim3 blk(256);

  CvtP cp{in_W, cc_W, Wq, Wk, Wv, Wo, c1W, c2W, bq, bk, bv, c1b,
          ln1g, ln1b, ln2g, ln2b,
          winb, wconv, wqkb, wkvb, wob, wc1, wc2,
          cgq, dq, cgkv, dkv, cg1, d1, t2pad};
  cvt_all<<<dim3(4096), blk, 0, stream>>>(cp);
  transpose_x<<<dim3(S_LEN / 64, 1, B_SZ), blk, 0, stream>>>(x, xT);

  GemmP p;
  auto clr = [&]() {
    p = GemmP{};
    p.lda = E_DIM; p.ldb = E_DIM; p.ldc = E_DIM;
  };

  // template args: TM,TN,ACT,READC,PADA,PADC,BIASROW,TRIMASK,SKIPUP,DIVDEN,
  //                TWOPH,CONV,SWZ,HALFK,LNM,SOUT
  // input projection -> padded bf16 latent (K=64)
  clr(); p.A = xT; p.B = winb; p.bias = in_b; p.Cb = t2pad;
  p.nkt = 1; p.lda = 64; p.ldb = 64;
  gemm_mfma<128,128,0,0,0,1,0,0,0,0,0,0,1,0,0,0><<<dim3(64,4), blk, 0, stream>>>(p);
  // fused causal conv (K=1536) -> latb, emits LN1 stats for layer 0
  clr(); p.A = t2pad; p.B = wconv; p.bias = cc_b; p.Cb = latb;
  p.nkt = 24; p.ldb = 1536; p.sout_ = stats1;
  gemm_mfma<128,128,0,0,1,0,0,0,0,0,0,1,1,0,0,1><<<dim3(64,4), blk, 0, stream>>>(p);

  for (int i = 0; i < L_NUM; ++i) {
    const size_t wOff = (size_t)i * E_DIM * E_DIM;
    const size_t bOff = (size_t)i * E_DIM;
    // MEGA: LN1-fused q|k GEMM || LN1-fused kT|vT GEMM (reads latb + stats1)
    GemmP pa{}; pa.lda = E_DIM; pa.ldb = E_DIM;
    pa.A = latb; pa.B = wqkb + (size_t)i * 524288;
    pa.Cb = qk; pa.nkt = 8; pa.ldc = QLD;
    pa.sin_ = stats1; pa.cg = cgq + i * 1024; pa.dv = dq + i * 1024;
    GemmP pb{}; pb.lda = E_DIM; pb.ldb = E_DIM;
    pb.A = wkvb + (size_t)i * 524288; pb.B = latb;
    pb.Cb = kvT; pb.nkt = 8; pb.ldc = ROWS;
    pb.sin_ = stats1; pb.cg = cgkv + i * 1024; pb.dv = dkv + i * 1024;
    mega_qkv<<<dim3(1024), blk, 0, stream>>>(pa, pb);
    // MEGA: chunk-KV P (chunk-7 skipped) || intra-chunk Sc || ksum tail
    GemmP pp{};
    pp.A = vT; pp.B = kT; pp.Cb = Pb; pp.nkt = 4;
    pp.lda = ROWS; pp.ldb = ROWS; pp.ldc = E_DIM;
    pp.aZcol = CHK; pp.bZcol = CHK; pp.cZrow = E_DIM;
    GemmP ps{};
    ps.A = qk; ps.B = qk + 512; ps.Cb = Sc; ps.nkt = 8;
    ps.lda = QLD; ps.ldb = QLD; ps.ldc = CHK;
    ps.aZrow = CHK; ps.bZrow = CHK; ps.cZrow = CHK;
    mega_psck<<<dim3(960), blk, 0, stream>>>(pp, ps, kT, ks);
    // merged: prefix (Pb->PTb) || den (rowsum(Sc) + q . inline-ks-prefix)
    misc_k<<<dim3(6144), blk, 0, stream>>>(Pb, PTb, Sc, qk, ks, den);
    // combine: (Sc@vT + q@PTb) / den -> t2b; causal K-trunc on Sc phase
    clr(); p.A = Sc; p.B = vT; p.Cb = t2b; p.den = den;
    p.nkt = 4; p.lda = CHK; p.ldb = ROWS; p.aZrow = CHK; p.bZcol = CHK;
    p.cZrow = CHK;
    p.A2 = qk; p.B2 = PTb; p.nkt2 = 8; p.lda2 = QLD; p.ldb2 = E_DIM;
    p.a2Zrow = CHK; p.b2Zrow = E_DIM;
    gemm_mfma<64,128,0,0,0,0,0,0,0,1,1,0,0,1,0,0><<<dim3(4,4,B_SZ*NCHK), blk, 0, stream>>>(p);
    // latb += t2b @ Wo^T + bo; emits LN2 stats
    clr(); p.A = t2b; p.B = wob + wOff; p.bias = bo + bOff; p.Cb = latb;
    p.nkt = 8; p.sout_ = stats2;
    gemm_mfma<64,128,0,1,0,0,0,0,0,0,0,0,1,0,0,1><<<dim3(128,4), blk, 0, stream>>>(p);
    // c1 (LN2-fused, gelu) -> t2b
    clr(); p.A = latb; p.B = wc1 + wOff; p.Cb = t2b; p.nkt = 8;
    p.sin_ = stats2; p.cg = cg1 + i * 512; p.dv = d1 + i * 512;
    gemm_mfma<64,128,2,0,0,0,0,0,0,0,0,0,1,0,1,0><<<dim3(128,4), blk, 0, stream>>>(p);
    // latb += t2b @ c2^T + c2b; emits LN1 stats for next layer
    clr(); p.A = t2b; p.B = wc2 + wOff; p.bias = c2b + bOff; p.Cb = latb;
    p.nkt = 8; p.sout_ = stats1;
    gemm_mfma<64,128,0,1,0,0,0,0,0,0,0,0,1,0,0,1><<<dim3(128,4), blk, 0, stream>>>(p);
  }
  out_proj<<<dim3(S_LEN / 64, 1, B_SZ), blk, 0, stream>>>(latb, oW, ob, out);
}

// Round 12
// 631.912 us; speedup vs baseline: 1.1379x; 1.1379x over previous
//
#include <hip/hip_runtime.h>
#include <hip/hip_bf16.h>
#include <cmath>

#define S_LEN 2048
#define E_DIM 512
#define B_SZ 4
#define CIN_D 64
#define COUT_D 64
#define L_NUM 4
#define CHK 256
#define NCHK 8
#define ROWS (B_SZ * S_LEN)  // 8192
#define PADR 2050            // padded rows per batch for causal conv
#define QLD 1024             // leading dim of fused qk buffer

typedef __attribute__((ext_vector_type(8))) short short8;
typedef __attribute__((ext_vector_type(4))) float f32x4;
typedef unsigned short ushort_t;

__device__ __forceinline__ ushort_t f2b(float v) {
  __hip_bfloat16 t = __float2bfloat16(v);
  return __builtin_bit_cast(ushort_t, t);
}
__device__ __forceinline__ float b2f(ushort_t u) {
  return __builtin_bit_cast(float, ((unsigned)u) << 16);
}
__device__ __forceinline__ float b2f(unsigned u) {
  return __builtin_bit_cast(float, u << 16);
}

__device__ __forceinline__ void gload16(const void* g, void* l) {
  __builtin_amdgcn_global_load_lds((const __attribute__((address_space(1))) void*)g,
                                   (__attribute__((address_space(3))) void*)l, 16, 0, 0);
}

__device__ __forceinline__ void barrier_mem() {
  asm volatile("s_barrier" ::: "memory");
}
template <int N>
__device__ __forceinline__ void waitn() {
  if constexpr (N == 0) asm volatile("s_waitcnt vmcnt(0)" ::: "memory");
  else if constexpr (N == 6) asm volatile("s_waitcnt vmcnt(6)" ::: "memory");
  else asm volatile("s_waitcnt vmcnt(8)" ::: "memory");
  __builtin_amdgcn_sched_barrier(0);
}

// ======================= universal bf16 MFMA GEMM =======================
struct GemmP {
  const ushort_t* A; const ushort_t* B; const float* bias;
  ushort_t* Cb; const float* den;
  int nkt, lda, ldb, ldc;
  int aZrow, aZcol, bZrow, bZcol, cZrow;
  const ushort_t* A2; const ushort_t* B2;
  int nkt2, lda2, ldb2, a2Zrow, b2Zrow;
};

template <int TM, int TN, bool CONV>
__device__ __forceinline__ void mma_phase(const ushort_t* A, const ushort_t* B,
                                          int nkt, int lda, int ldb, int arow0,
                                          int acol0, int brow0, int bcol0,
                                          char* sm, int tid,
                                          f32x4 (&acc)[TM / 32][TN / 32]) {
  constexpr int MF = TM / 32, NF = TN / 32;
  constexpr int ABY = TM * 128, BBY = TN * 128, BUF = ABY + BBY;
  constexpr int RA = ABY / 4096, RB = BBY / 4096;
  const int lane = tid & 63, w = tid >> 6;
  const int wr = (w >> 1) * (TM / 2), wc = (w & 1) * (TN / 2);
  const int l15 = lane & 15, l4 = lane >> 4;

  auto stage = [&](int kt, int buf) {
    int ar0 = arow0, ac0 = acol0 + (kt << 6);
    if (CONV) {
      ar0 = arow0 + (kt >> 3);
      ac0 = acol0 + ((kt & 7) << 6);
    }
    char* s = sm + buf * BUF;
#pragma unroll
    for (int r = 0; r < RA; ++r) {
      const int f = (r << 12) + (tid << 4);
      const int row = f >> 7, sw = ((((f >> 4) & 7)) ^ (row & 7)) << 3;
      gload16(A + (size_t)(ar0 + row) * lda + ac0 + sw, s + f);
    }
    const int bc0 = bcol0 + (kt << 6);
#pragma unroll
    for (int r = 0; r < RB; ++r) {
      const int f = (r << 12) + (tid << 4);
      const int row = f >> 7, sw = ((((f >> 4) & 7)) ^ (row & 7)) << 3;
      gload16(B + (size_t)(brow0 + row) * ldb + bc0 + sw, s + ABY + f);
    }
  };

  stage(0, 0);
  int cur = 0;
  for (int kt = 0; kt < nkt; ++kt) {
    if (kt + 1 < nkt) {
      stage(kt + 1, cur ^ 1);  // prefetch next tile
      waitn<RA + RB>();        // wait ONLY the older (current) tile
    } else {
      waitn<0>();
    }
    barrier_mem();
    char* s = sm + cur * BUF;
#pragma unroll
    for (int kk = 0; kk < 2; ++kk) {
      short8 af[MF], bfv[NF];
#pragma unroll
      for (int m = 0; m < MF; ++m) {
        const int rt = wr + (m << 4) + l15;
        af[m] = *(const short8*)(s + rt * 128 +
                                 (((kk << 6) + (l4 << 4)) ^ ((rt & 7) << 4)));
      }
#pragma unroll
      for (int n = 0; n < NF; ++n) {
        const int rt = wc + (n << 4) + l15;
        bfv[n] = *(const short8*)(s + ABY + rt * 128 +
                                  (((kk << 6) + (l4 << 4)) ^ ((rt & 7) << 4)));
      }
#pragma unroll
      for (int m = 0; m < MF; ++m)
#pragma unroll
        for (int n = 0; n < NF; ++n)
          acc[m][n] = __builtin_amdgcn_mfma_f32_16x16x32_bf16(af[m], bfv[n],
                                                              acc[m][n], 0, 0, 0);
    }
    __builtin_amdgcn_sched_barrier(0);
    asm volatile("s_waitcnt lgkmcnt(0)" ::: "memory");
    barrier_mem();
    cur ^= 1;
  }
}

// ACT: 0 none, 1 phi, 2 gelu, 3 phi-if-row<512 (fused k|v)
template <int TM, int TN, int ACT, bool READC, bool PADA, bool PADC,
          bool BIASROW, bool TRIMASK, bool SKIPUP, bool DIVDEN, bool TWOPH,
          bool CONV, bool HALFK>
__device__ __forceinline__ void gemm_body(const GemmP& p, int bm, int bn,
                                          int z, int tid, char* smem) {
  constexpr int MF = TM / 32, NF = TN / 32;
  const int lane = tid & 63, w = tid >> 6;
  const int wr = (w >> 1) * (TM / 2), wc = (w & 1) * (TN / 2);
  const int l15 = lane & 15, l4 = lane >> 4;

  if (SKIPUP && bn >= bm + TM) {  // fully-masked tile: zero-fill Cb
#pragma unroll
    for (int m = 0; m < MF; ++m)
#pragma unroll
      for (int j = 0; j < 4; ++j) {
        const int rloc = bm + wr + (m << 4) + (l4 << 2) + j;
        const size_t crow = (size_t)p.cZrow * z + rloc;
#pragma unroll
        for (int n = 0; n < NF; ++n)
          p.Cb[crow * p.ldc + bn + wc + (n << 4) + l15] = 0;
      }
    return;
  }

  f32x4 acc[MF][NF];
#pragma unroll
  for (int m = 0; m < MF; ++m)
#pragma unroll
    for (int n = 0; n < NF; ++n)
#pragma unroll
      for (int j = 0; j < 4; ++j) acc[m][n][j] = 0.f;

  int arow0 = bm + p.aZrow * z;
  if (PADA) arow0 = bm + ((bm >> 11) << 1);  // padded batch base
  int nkt1 = p.nkt;
  if (HALFK) nkt1 = min(p.nkt, (bm + TM) >> 6);  // causal K truncation
  mma_phase<TM, TN, CONV>(p.A, p.B, nkt1, p.lda, p.ldb, arow0, p.aZcol * z,
                          bn + p.bZrow * z, p.bZcol * z, smem, tid, acc);
  if (TWOPH)
    mma_phase<TM, TN, false>(p.A2, p.B2, p.nkt2, p.lda2, p.ldb2,
                             bm + p.a2Zrow * z, 0, bn + p.b2Zrow * z, 0, smem,
                             tid, acc);

  float bcol[NF];
  if (p.bias && !BIASROW) {
#pragma unroll
    for (int n = 0; n < NF; ++n) bcol[n] = p.bias[bn + wc + (n << 4) + l15];
  }
  int crow_base = bm;
  if (PADC) crow_base = bm + ((bm >> 11) << 1) + 2;
#pragma unroll
  for (int m = 0; m < MF; ++m) {
#pragma unroll
    for (int j = 0; j < 4; ++j) {
      const int rloc = wr + (m << 4) + (l4 << 2) + j;
      const size_t crow = (size_t)p.cZrow * z + crow_base + rloc;
      float inv = 1.f;
      if (DIVDEN) inv = 1.f / (p.den[crow] + 1e-6f);
      float brbias = 0.f;
      if (BIASROW && p.bias) brbias = p.bias[bm + rloc];
#pragma unroll
      for (int n = 0; n < NF; ++n) {
        const int col = bn + wc + (n << 4) + l15;
        float v = acc[m][n][j];
        if (p.bias) v += BIASROW ? brbias : bcol[n];
        if (ACT == 1) v = v > 0.f ? v + 1.f : __expf(v);
        if (ACT == 2) v = 0.5f * v * (1.f + erff(v * 0.70710678118654752f));
        if (ACT == 3 && (bm + rloc) < 512) v = v > 0.f ? v + 1.f : __expf(v);
        if (TRIMASK) {
          if (col > bm + rloc) v = 0.f;
        }
        const size_t cidx = crow * p.ldc + col;
        if (READC) v += b2f(p.Cb[cidx]);
        if (DIVDEN) v *= inv;
        p.Cb[cidx] = f2b(v);
      }
    }
  }
}

__device__ __forceinline__ void swz_decode(int r, int gx, int gy, int swz,
                                           int& bx, int& by) {
  if (swz) {
    const int per = gx * gy, cpx = per >> 3;
    const int s = (r & 7) * cpx + (r >> 3);
    if (gx >= gy) { bx = s / gy; by = s % gy; }
    else          { by = s / gx; bx = s % gx; }
  } else {
    bx = r % gx;
    by = r / gx;
  }
}

template <int TM, int TN, int ACT, bool READC, bool PADA, bool PADC,
          bool BIASROW, bool TRIMASK, bool SKIPUP, bool DIVDEN, bool TWOPH,
          bool CONV, bool SWZ, bool HALFK>
__global__ __launch_bounds__(256) void gemm_mfma(GemmP p) {
  __shared__ __align__(16) char smem[2 * (TM + TN) * 128];
  int bxx = blockIdx.x, byy = blockIdx.y;
  if (SWZ) {
    const int gx = gridDim.x, gy = gridDim.y;
    swz_decode(byy * gx + bxx, gx, gy, 1, bxx, byy);
  }
  gemm_body<TM, TN, ACT, READC, PADA, PADC, BIASROW, TRIMASK, SKIPUP, DIVDEN,
            TWOPH, CONV, HALFK>(p, bxx * TM, byy * TN, blockIdx.z, threadIdx.x,
                                smem);
}

// ======================= small phase bodies =======================

__device__ __forceinline__ void ksum_body(const ushort_t* __restrict__ kT,
                                          float* __restrict__ ks, int unit,
                                          int nunits, int tid) {
  const int wid = tid >> 6, lane = tid & 63;
  const int nw = nunits << 2;
  for (int it = (unit << 2) + wid; it < B_SZ * 7 * E_DIM; it += nw) {
    const int zi = it >> 9, e = it & 511;
    const int z = ((zi / 7) << 3) + zi % 7;
    const uint2 u =
        *(const uint2*)(kT + (size_t)e * ROWS + (z << 8) + (lane << 2));
    float s = b2f(u.x & 0xffffu) + b2f(u.x >> 16) + b2f(u.y & 0xffffu) +
              b2f(u.y >> 16);
#pragma unroll
    for (int off = 32; off; off >>= 1) s += __shfl_xor(s, off);
    if (lane == 0) ks[(z << 9) + e] = s;
  }
}

// ============ mega kernels: template-specialized multi-GEMM launches ========

// qk (128x128, ACT=phi, swz grid 64x8) || kvT (128x128, ACT=3, BIASROW, 8x64)
__global__ __launch_bounds__(256) void mega_qkv(GemmP pa, GemmP pb) {
  __shared__ __align__(16) char smem[65536];
  const int tid = threadIdx.x;
  const int bid = blockIdx.x;
  if (bid < 512) {
    int bx, by;
    swz_decode(bid, 64, 8, 1, bx, by);
    gemm_body<128, 128, 1, 0, 0, 0, 0, 0, 0, 0, 0, 0, 0>(pa, bx << 7, by << 7,
                                                          0, tid, smem);
  } else {
    int bx, by;
    swz_decode(bid - 512, 8, 64, 1, bx, by);
    gemm_body<128, 128, 3, 0, 0, 0, 1, 0, 0, 0, 0, 0, 0>(pb, bx << 7, by << 7,
                                                          0, tid, smem);
  }
}

// P (128x128, z in 28 chunks) || Sc (128x64, TRIMASK+SKIPUP) || ksum tail
__global__ __launch_bounds__(256) void mega_psck(GemmP pp, GemmP ps,
                                                 const ushort_t* kT,
                                                 float* ks) {
  __shared__ __align__(16) char smem[65536];
  const int tid = threadIdx.x;
  const int bid = blockIdx.x;
  if (bid < 448) {  // P-GEMM, chunk-7 skipped
    int z = bid >> 4;
    z = (z / 7) * 8 + z % 7;
    const int r = bid & 15;
    gemm_body<128, 128, 0, 0, 0, 0, 0, 0, 0, 0, 0, 0, 0>(
        pp, (r & 3) << 7, (r >> 2) << 7, z, tid, smem);
  } else if (bid < 704) {  // intra-chunk scores
    const int v = bid - 448;
    const int z = v >> 3, r = v & 7;
    gemm_body<128, 64, 0, 0, 0, 0, 0, 1, 1, 0, 0, 0, 0>(
        ps, (r & 1) << 7, (r >> 1) << 6, z, tid, smem);
  } else {
    ksum_body(kT, ks, bid - 704, 256, tid);
  }
}

// ======================= prep kernel (vectorized, + transpose tail) =========

struct CvtP {
  const float *in_W, *cc_W, *Wq, *Wk, *Wv, *Wo, *c1W, *c2W, *bq, *bk, *bv;
  ushort_t *winb, *wconv, *wqkb, *wkvb, *wob, *wc1, *wc2;
  float *bqk, *bkv;
  ushort_t* t2pad;
  const float* x; ushort_t* xT;
};

__device__ __forceinline__ void cvt8(const float* s, ushort_t* d) {
  const float4 a = *(const float4*)s;
  const float4 b = *(const float4*)(s + 4);
  uint4 o;
  o.x = ((unsigned)f2b(a.y) << 16) | f2b(a.x);
  o.y = ((unsigned)f2b(a.w) << 16) | f2b(a.z);
  o.z = ((unsigned)f2b(b.y) << 16) | f2b(b.x);
  o.w = ((unsigned)f2b(b.w) << 16) | f2b(b.z);
  *(uint4*)d = o;
}

#define NB_CVT 2048
__global__ __launch_bounds__(256) void cvt_all(CvtP c) {
  __shared__ float t[64][65];
  const int tid = threadIdx.x;
  if (blockIdx.x >= NB_CVT) {  // transpose_x tail: 128 blocks
    const int v = blockIdx.x - NB_CVT;  // 0..127
    const int b = v >> 5, s0 = (v & 31) << 6;
#pragma unroll
    for (int i = 0; i < 16; ++i) {
      int idx = tid + (i << 8);
      int ch = idx >> 6, s = idx & 63;
      t[ch][s] = c.x[(((size_t)(b * CIN_D + ch)) << 11) + s0 + s];
    }
    __syncthreads();
#pragma unroll
    for (int i = 0; i < 16; ++i) {
      int idx = tid + (i << 8);
      int s = idx >> 6, ch = idx & 63;
      c.xT[(((size_t)(b * S_LEN + s0 + s)) << 6) + ch] = f2b(t[ch][s]);
    }
    return;
  }
  // vectorized conversion: units of 8 elements; all section sizes are 8-aligned
  const size_t NU = (32768 + 786432 + 2097152 * 2 + 1048576 * 3 + 4096 * 2 +
                     4096) >> 3;
  for (size_t iu = (size_t)blockIdx.x * 256 + tid; iu < NU;
       iu += (size_t)NB_CVT * 256) {
    size_t j = iu << 3;
    if (j < 32768) { cvt8(c.in_W + j, c.winb + j); continue; }
    j -= 32768;
    if (j < 786432) {  // wconv[n][tap*512+k] = cc_W[n][k][tap], stride-3 gather
      size_t n = j / 1536, r = j % 1536;
      const float* src = c.cc_W + n * 1536 + (r & 511) * 3 + (r >> 9);
      float v[8];
#pragma unroll
      for (int tS = 0; tS < 8; ++tS) v[tS] = src[tS * 3];
      uint4 o;
      o.x = ((unsigned)f2b(v[1]) << 16) | f2b(v[0]);
      o.y = ((unsigned)f2b(v[3]) << 16) | f2b(v[2]);
      o.z = ((unsigned)f2b(v[5]) << 16) | f2b(v[4]);
      o.w = ((unsigned)f2b(v[7]) << 16) | f2b(v[6]);
      *(uint4*)(c.wconv + j) = o;
      continue;
    }
    j -= 786432;
    if (j < 2097152) {  // wqkb = [Wq;Wk]
      size_t l = j >> 19, r = j & 524287, row = r >> 9, k = r & 511;
      const float* src = row < 512
                             ? c.Wq + l * 262144 + row * 512 + k
                             : c.Wk + l * 262144 + (row - 512) * 512 + k;
      cvt8(src, c.wqkb + j);
      continue;
    }
    j -= 2097152;
    if (j < 2097152) {  // wkvb = [Wk;Wv]
      size_t l = j >> 19, r = j & 524287, row = r >> 9, k = r & 511;
      const float* src = row < 512
                             ? c.Wk + l * 262144 + row * 512 + k
                             : c.Wv + l * 262144 + (row - 512) * 512 + k;
      cvt8(src, c.wkvb + j);
      continue;
    }
    j -= 2097152;
    if (j < 1048576) { cvt8(c.Wo + j, c.wob + j); continue; }
    j -= 1048576;
    if (j < 1048576) { cvt8(c.c1W + j, c.wc1 + j); continue; }
    j -= 1048576;
    if (j < 1048576) { cvt8(c.c2W + j, c.wc2 + j); continue; }
    j -= 1048576;
    if (j < 4096) {  // bqk floats
      size_t l = j >> 10, r = j & 1023;
      const float* src = r < 512 ? c.bq + l * 512 + r : c.bk + l * 512 + r - 512;
      *(float4*)(c.bqk + j) = *(const float4*)src;
      *(float4*)(c.bqk + j + 4) = *(const float4*)(src + 4);
      continue;
    }
    j -= 4096;
    if (j < 4096) {  // bkv floats
      size_t l = j >> 10, r = j & 1023;
      const float* src = r < 512 ? c.bk + l * 512 + r : c.bv + l * 512 + r - 512;
      *(float4*)(c.bkv + j) = *(const float4*)src;
      *(float4*)(c.bkv + j + 4) = *(const float4*)(src + 4);
      continue;
    }
    j -= 4096;
    {  // zero-fill the 2 pad rows at each batch start of t2pad
      int b = (int)(j >> 10), r = (int)(j & 1023);
      uint4 z4{0, 0, 0, 0};
      *(uint4*)(c.t2pad + (size_t)(b * PADR) * E_DIM + r) = z4;
    }
  }
}

// wave-per-row layernorm over bf16 latent: 4 rows / block
__global__ __launch_bounds__(256) void layernorm_b(const ushort_t* __restrict__ x,
                                                   const float* __restrict__ g,
                                                   const float* __restrict__ bb,
                                                   ushort_t* __restrict__ y) {
  const int wid = threadIdx.x >> 6, lane = threadIdx.x & 63;
  const int row = (blockIdx.x << 2) + wid;
  const ushort_t* xr = x + ((size_t)row << 9);
  const uint4 u = *(const uint4*)(xr + (lane << 3));  // 8 bf16
  float v[8];
  v[0] = b2f(u.x & 0xffffu); v[1] = b2f(u.x >> 16);
  v[2] = b2f(u.y & 0xffffu); v[3] = b2f(u.y >> 16);
  v[4] = b2f(u.z & 0xffffu); v[5] = b2f(u.z >> 16);
  v[6] = b2f(u.w & 0xffffu); v[7] = b2f(u.w >> 16);
  float s = 0.f, q2 = 0.f;
#pragma unroll
  for (int i = 0; i < 8; ++i) { s += v[i]; q2 += v[i] * v[i]; }
#pragma unroll
  for (int off = 32; off; off >>= 1) {
    s += __shfl_xor(s, off);
    q2 += __shfl_xor(q2, off);
  }
  const float m = s * (1.f / 512.f);
  const float r = rsqrtf(q2 * (1.f / 512.f) - m * m + 1e-5f);
  const int c = lane << 3;
  const float4 g0 = *(const float4*)(g + c);
  const float4 g1 = *(const float4*)(g + c + 4);
  const float4 b0 = *(const float4*)(bb + c);
  const float4 b1 = *(const float4*)(bb + c + 4);
  uint4 o;
  o.x = ((unsigned)f2b((v[1] - m) * r * g0.y + b0.y) << 16) |
        f2b((v[0] - m) * r * g0.x + b0.x);
  o.y = ((unsigned)f2b((v[3] - m) * r * g0.w + b0.w) << 16) |
        f2b((v[2] - m) * r * g0.z + b0.z);
  o.z = ((unsigned)f2b((v[5] - m) * r * g1.y + b1.y) << 16) |
        f2b((v[4] - m) * r * g1.x + b1.x);
  o.w = ((unsigned)f2b((v[7] - m) * r * g1.w + b1.w) << 16) |
        f2b((v[6] - m) * r * g1.z + b1.z);
  *(uint4*)(y + ((size_t)row << 9) + c) = o;
}

// merged: blocks 0..4095 = exclusive chunk prefix Pb->PTb (bf16, fp32 acc;
//         chunk-7 Pb never computed -> skipped);
//         blocks 4096..6143 = den (wave per row, ks prefix inlined)
__global__ __launch_bounds__(256) void misc_k(
    const ushort_t* __restrict__ Pb, ushort_t* __restrict__ PTb,
    const ushort_t* __restrict__ Sc, const ushort_t* __restrict__ qk,
    const float* __restrict__ ksum, float* __restrict__ den) {
  int bid = blockIdx.x;
  if (bid < 4096) {
    const size_t idx = ((size_t)bid << 8) + threadIdx.x;  // < B*E*E
    const int b = (int)(idx >> 18);
    const size_t r = idx & ((1u << 18) - 1);
    float acc = 0.f;
#pragma unroll
    for (int j = 0; j < NCHK; ++j) {
      const size_t o = (((size_t)(b * NCHK + j)) << 18) + r;
      PTb[o] = f2b(acc);
      if (j < NCHK - 1) acc += b2f(Pb[o]);
    }
  } else {
    bid -= 4096;
    const int wid = threadIdx.x >> 6, lane = threadIdx.x & 63;
    const int row = (bid << 2) + wid;  // < 8192
    const int z = row >> 8, sl = row & 255;
    const ushort_t* sr = Sc + (((size_t)z) << 16) + ((size_t)sl << 8);
    float s = 0.f;
#pragma unroll
    for (int t = 0; t < 4; ++t) s += b2f(sr[lane + (t << 6)]);
    const ushort_t* qr = qk + (size_t)row * QLD;
    const int j0 = z & ~7;
    for (int e = lane; e < E_DIM; e += 64) {
      float kp = 0.f;
      for (int j = j0; j < z; ++j) kp += ksum[(j << 9) + e];
      s += b2f(qr[e]) * kp;
    }
#pragma unroll
    for (int off = 32; off; off >>= 1) s += __shfl_xor(s, off);
    if (lane == 0) den[row] = s;
  }
}

__global__ __launch_bounds__(256) void out_proj(const ushort_t* __restrict__ lat,
                                                const float* __restrict__ W,
                                                const float* __restrict__ bias,
                                                float* __restrict__ out) {
  const int b = blockIdx.z, bs = blockIdx.x << 6;
  const int tid = threadIdx.x, tm = tid >> 4, tn = tid & 15;
  const int lr = tid >> 2, lc = (tid & 3) << 2;
  __shared__ float As[16][64], Ws[16][64];
  float acc[4][4] = {{0.f}};
  for (int k0 = 0; k0 < E_DIM; k0 += 16) {
    const uint2 ra =
        *(const uint2*)(lat + (((size_t)(b * S_LEN + bs + lr)) << 9) + k0 + lc);
    As[lc + 0][lr] = b2f(ra.x & 0xffffu);
    As[lc + 1][lr] = b2f(ra.x >> 16);
    As[lc + 2][lr] = b2f(ra.y & 0xffffu);
    As[lc + 3][lr] = b2f(ra.y >> 16);
    float4 wv = *(const float4*)(W + (((size_t)lr) << 9) + k0 + lc);
    Ws[lc + 0][lr] = wv.x; Ws[lc + 1][lr] = wv.y;
    Ws[lc + 2][lr] = wv.z; Ws[lc + 3][lr] = wv.w;
    __syncthreads();
#pragma unroll
    for (int kk = 0; kk < 16; ++kk) {
      const float4 a4 = *(const float4*)&As[kk][tm << 2];
      const float4 b4 = *(const float4*)&Ws[kk][tn << 2];
      const float aa[4] = {a4.x, a4.y, a4.z, a4.w};
      const float bb[4] = {b4.x, b4.y, b4.z, b4.w};
#pragma unroll
      for (int i = 0; i < 4; ++i)
#pragma unroll
        for (int j2 = 0; j2 < 4; ++j2) acc[i][j2] += aa[i] * bb[j2];
    }
    __syncthreads();
  }
#pragma unroll
  for (int i = 0; i < 4; ++i)
#pragma unroll
    for (int j2 = 0; j2 < 4; ++j2) {
      const int o = (tn << 2) + j2, sl = bs + (tm << 2) + i;
      out[(((size_t)(b * COUT_D + o)) << 11) + sl] = acc[i][j2] + bias[o];
    }
}

// ======================= host launcher =======================
extern "C" void kernel_launch(void* const* d_in, const int* in_sizes, int n_in,
                              void* d_out, int out_size, void* d_ws,
                              size_t ws_size, hipStream_t stream) {
  const float* x = (const float*)d_in[0];
  const float* in_W = (const float*)d_in[1];
  const float* in_b = (const float*)d_in[2];
  const float* cc_W = (const float*)d_in[3];
  const float* cc_b = (const float*)d_in[4];
  const float* ln1g = (const float*)d_in[5];
  const float* ln1b = (const float*)d_in[6];
  const float* ln2g = (const float*)d_in[7];
  const float* ln2b = (const float*)d_in[8];
  const float* Wq = (const float*)d_in[9];
  const float* bq = (const float*)d_in[10];
  const float* Wk = (const float*)d_in[11];
  const float* bk = (const float*)d_in[12];
  const float* Wv = (const float*)d_in[13];
  const float* bv = (const float*)d_in[14];
  const float* Wo = (const float*)d_in[15];
  const float* bo = (const float*)d_in[16];
  const float* c1W = (const float*)d_in[17];
  const float* c1b = (const float*)d_in[18];
  const float* c2W = (const float*)d_in[19];
  const float* c2b = (const float*)d_in[20];
  const float* oW = (const float*)d_in[21];
  const float* ob = (const float*)d_in[22];
  float* out = (float*)d_out;

  const size_t NE = (size_t)ROWS * E_DIM;  // 4194304
  float* ks = (float*)d_ws;  // 16384
  float* den = ks + 16384;   // 8192
  float* bqk = den + 8192;   // 4096
  float* bkv = bqk + 4096;   // 4096
  ushort_t* u = (ushort_t*)(bkv + 4096);
  ushort_t* latb = u;   u += NE;
  ushort_t* Pb = u;     u += 8388608;
  ushort_t* xT = u;     u += (size_t)ROWS * CIN_D;
  ushort_t* t2pad = u;  u += (size_t)B_SZ * PADR * E_DIM;
  ushort_t* h = u;      u += NE;
  ushort_t* qk = u;     u += (size_t)ROWS * QLD;
  ushort_t* kvT = u;    u += (size_t)1024 * ROWS;
  ushort_t* PTb = u;    u += 8388608;
  ushort_t* t2b = u;    u += NE;
  ushort_t* winb = u;   u += 32768;
  ushort_t* wconv = u;  u += 786432;
  ushort_t* wqkb = u;   u += 2097152;
  ushort_t* wkvb = u;   u += 2097152;
  ushort_t* wob = u;    u += 1048576;
  ushort_t* wc1 = u;    u += 1048576;
  ushort_t* wc2 = u;    u += 1048576;
  ushort_t* Sc = t2pad;  // alias: t2pad dead after conv
  ushort_t* kT = kvT;
  ushort_t* vT = kvT + (size_t)512 * ROWS;

  const dim3 blk(256);

  CvtP cp{in_W, cc_W, Wq, Wk, Wv, Wo, c1W, c2W, bq, bk, bv,
          winb, wconv, wqkb, wkvb, wob, wc1, wc2, bqk, bkv, t2pad, x, xT};
  cvt_all<<<dim3(NB_CVT + 128), blk, 0, stream>>>(cp);

  GemmP p;
  auto clr = [&]() {
    p = GemmP{};
    p.lda = E_DIM; p.ldb = E_DIM; p.ldc = E_DIM;
  };

  // template args: TM,TN,ACT,READC,PADA,PADC,BIASROW,TRIMASK,SKIPUP,DIVDEN,
  //                TWOPH,CONV,SWZ,HALFK
  // input projection -> padded bf16 latent (K=64)
  clr(); p.A = xT; p.B = winb; p.bias = in_b; p.Cb = t2pad;
  p.nkt = 1; p.lda = 64; p.ldb = 64;
  gemm_mfma<128,128,0,0,0,1,0,0,0,0,0,0,1,0><<<dim3(64,4), blk, 0, stream>>>(p);
  // fused causal conv: one GEMM, K=1536 (3 taps x 512) -> latb (bf16)
  clr(); p.A = t2pad; p.B = wconv; p.bias = cc_b; p.Cb = latb;
  p.nkt = 24; p.ldb = 1536;
  gemm_mfma<128,128,0,0,1,0,0,0,0,0,0,1,1,0><<<dim3(64,4), blk, 0, stream>>>(p);

  for (int i = 0; i < L_NUM; ++i) {
    const size_t wOff = (size_t)i * E_DIM * E_DIM;
    const size_t bOff = (size_t)i * E_DIM;
    layernorm_b<<<dim3(ROWS / 4), blk, 0, stream>>>(latb, ln1g + bOff,
                                                    ln1b + bOff, h);
    // MEGA: fused q|k GEMM || fused kT|vT GEMM (template-specialized)
    GemmP pa{}; pa.lda = E_DIM; pa.ldb = E_DIM;
    pa.A = h; pa.B = wqkb + (size_t)i * 524288; pa.bias = bqk + i * 1024;
    pa.Cb = qk; pa.nkt = 8; pa.ldc = QLD;
    GemmP pb{}; pb.lda = E_DIM; pb.ldb = E_DIM;
    pb.A = wkvb + (size_t)i * 524288; pb.B = h; pb.bias = bkv + i * 1024;
    pb.Cb = kvT; pb.nkt = 8; pb.ldc = ROWS;
    mega_qkv<<<dim3(1024), blk, 0, stream>>>(pa, pb);
    // MEGA: chunk-KV P (chunk-7 skipped) || intra-chunk Sc || ksum tail
    GemmP pp{};
    pp.A = vT; pp.B = kT; pp.Cb = Pb; pp.nkt = 4;
    pp.lda = ROWS; pp.ldb = ROWS; pp.ldc = E_DIM;
    pp.aZcol = CHK; pp.bZcol = CHK; pp.cZrow = E_DIM;
    GemmP ps{};
    ps.A = qk; ps.B = qk + 512; ps.Cb = Sc; ps.nkt = 8;
    ps.lda = QLD; ps.ldb = QLD; ps.ldc = CHK;
    ps.aZrow = CHK; ps.bZrow = CHK; ps.cZrow = CHK;
    mega_psck<<<dim3(960), blk, 0, stream>>>(pp, ps, kT, ks);
    // merged: prefix (Pb->PTb) || den (rowsum(Sc) + q . inline-ks-prefix)
    misc_k<<<dim3(6144), blk, 0, stream>>>(Pb, PTb, Sc, qk, ks, den);
    // combine: (Sc@vT + q@PTb) / den -> t2b (bf16); causal K-trunc on Sc phase
    clr(); p.A = Sc; p.B = vT; p.Cb = t2b; p.den = den;
    p.nkt = 4; p.lda = CHK; p.ldb = ROWS; p.aZrow = CHK; p.bZcol = CHK;
    p.cZrow = CHK;
    p.A2 = qk; p.B2 = PTb; p.nkt2 = 8; p.lda2 = QLD; p.ldb2 = E_DIM;
    p.a2Zrow = CHK; p.b2Zrow = E_DIM;
    gemm_mfma<64,128,0,0,0,0,0,0,0,1,1,0,0,1><<<dim3(4,4,B_SZ*NCHK), blk, 0, stream>>>(p);
    // latb += t2b @ Wo^T  (bf16 residual RMW)
    clr(); p.A = t2b; p.B = wob + wOff; p.bias = bo + bOff; p.Cb = latb;
    p.nkt = 8;
    gemm_mfma<64,128,0,1,0,0,0,0,0,0,0,0,1,0><<<dim3(128,4), blk, 0, stream>>>(p);
    layernorm_b<<<dim3(ROWS / 4), blk, 0, stream>>>(latb, ln2g + bOff,
                                                    ln2b + bOff, h);
    // c1 (gelu) -> t2b ; latb += t2b @ c2^T
    clr(); p.A = h; p.B = wc1 + wOff; p.bias = c1b + bOff; p.Cb = t2b;
    p.nkt = 8;
    gemm_mfma<64,128,2,0,0,0,0,0,0,0,0,0,1,0><<<dim3(128,4), blk, 0, stream>>>(p);
    clr(); p.A = t2b; p.B = wc2 + wOff; p.bias = c2b + bOff; p.Cb = latb;
    p.nkt = 8;
    gemm_mfma<64,128,0,1,0,0,0,0,0,0,0,0,1,0><<<dim3(128,4), blk, 0, stream>>>(p);
  }
  out_proj<<<dim3(S_LEN / 64, 1, B_SZ), blk, 0, stream>>>(latb, oW, ob, out);
}

// Round 13
// 590.365 us; speedup vs baseline: 1.2180x; 1.0704x over previous
//
#include <hip/hip_runtime.h>
#include <hip/hip_bf16.h>
#include <cmath>

#define S_LEN 2048
#define E_DIM 512
#define B_SZ 4
#define CIN_D 64
#define COUT_D 64
#define L_NUM 4
#define CHK 256
#define NCHK 8
#define ROWS (B_SZ * S_LEN)  // 8192
#define PADR 2050            // padded rows per batch for causal conv
#define QLD 1024             // leading dim of fused qk buffer

typedef __attribute__((ext_vector_type(8))) short short8;
typedef __attribute__((ext_vector_type(4))) float f32x4;
typedef unsigned short ushort_t;

__device__ __forceinline__ ushort_t f2b(float v) {
  __hip_bfloat16 t = __float2bfloat16(v);
  return __builtin_bit_cast(ushort_t, t);
}
__device__ __forceinline__ float b2f(ushort_t u) {
  return __builtin_bit_cast(float, ((unsigned)u) << 16);
}
__device__ __forceinline__ float b2f(unsigned u) {
  return __builtin_bit_cast(float, u << 16);
}

__device__ __forceinline__ void gload16(const void* g, void* l) {
  __builtin_amdgcn_global_load_lds((const __attribute__((address_space(1))) void*)g,
                                   (__attribute__((address_space(3))) void*)l, 16, 0, 0);
}

__device__ __forceinline__ void barrier_mem() {
  asm volatile("s_barrier" ::: "memory");
}
template <int N>
__device__ __forceinline__ void waitn() {
  if constexpr (N == 0) asm volatile("s_waitcnt vmcnt(0)" ::: "memory");
  else if constexpr (N == 6) asm volatile("s_waitcnt vmcnt(6)" ::: "memory");
  else asm volatile("s_waitcnt vmcnt(8)" ::: "memory");
  __builtin_amdgcn_sched_barrier(0);
}

// ======================= universal bf16 MFMA GEMM =======================
// B-fragment n maps lane l15 -> LDS row (wc + l15*NF + n) so each lane's NF
// output columns are CONSECUTIVE -> vectorized (packed bf16) epilogue.
// B-side LDS swizzle uses f(row)=(row>>2)&7 (2-way alias = free for both
// NF=4 and NF=2 read patterns); A-side keeps f(row)=row&7.
struct GemmP {
  const ushort_t* A; const ushort_t* B; const float* bias;
  ushort_t* Cb; const float* den;
  int nkt, lda, ldb, ldc;
  int aZrow, aZcol, bZrow, bZcol, cZrow;
  const ushort_t* A2; const ushort_t* B2;
  int nkt2, lda2, ldb2, a2Zrow, b2Zrow;
};

template <int TM, int TN, bool CONV>
__device__ __forceinline__ void mma_phase(const ushort_t* A, const ushort_t* B,
                                          int nkt, int lda, int ldb, int arow0,
                                          int acol0, int brow0, int bcol0,
                                          char* sm, int tid,
                                          f32x4 (&acc)[TM / 32][TN / 32]) {
  constexpr int MF = TM / 32, NF = TN / 32;
  constexpr int ABY = TM * 128, BBY = TN * 128, BUF = ABY + BBY;
  constexpr int RA = ABY / 4096, RB = BBY / 4096;
  const int lane = tid & 63, w = tid >> 6;
  const int wr = (w >> 1) * (TM / 2), wc = (w & 1) * (TN / 2);
  const int l15 = lane & 15, l4 = lane >> 4;

  auto stage = [&](int kt, int buf) {
    int ar0 = arow0, ac0 = acol0 + (kt << 6);
    if (CONV) {
      ar0 = arow0 + (kt >> 3);
      ac0 = acol0 + ((kt & 7) << 6);
    }
    char* s = sm + buf * BUF;
#pragma unroll
    for (int r = 0; r < RA; ++r) {
      const int f = (r << 12) + (tid << 4);
      const int row = f >> 7, sw = ((((f >> 4) & 7)) ^ (row & 7)) << 3;
      gload16(A + (size_t)(ar0 + row) * lda + ac0 + sw, s + f);
    }
    const int bc0 = bcol0 + (kt << 6);
#pragma unroll
    for (int r = 0; r < RB; ++r) {
      const int f = (r << 12) + (tid << 4);
      const int row = f >> 7, sw = ((((f >> 4) & 7)) ^ ((row >> 2) & 7)) << 3;
      gload16(B + (size_t)(brow0 + row) * ldb + bc0 + sw, s + ABY + f);
    }
  };

  stage(0, 0);
  int cur = 0;
  for (int kt = 0; kt < nkt; ++kt) {
    if (kt + 1 < nkt) {
      stage(kt + 1, cur ^ 1);  // prefetch next tile
      waitn<RA + RB>();        // wait ONLY the older (current) tile
    } else {
      waitn<0>();
    }
    barrier_mem();
    char* s = sm + cur * BUF;
#pragma unroll
    for (int kk = 0; kk < 2; ++kk) {
      short8 af[MF], bfv[NF];
#pragma unroll
      for (int m = 0; m < MF; ++m) {
        const int rt = wr + (m << 4) + l15;
        af[m] = *(const short8*)(s + rt * 128 +
                                 (((kk << 6) + (l4 << 4)) ^ ((rt & 7) << 4)));
      }
#pragma unroll
      for (int n = 0; n < NF; ++n) {
        const int rt = wc + l15 * NF + n;
        bfv[n] = *(const short8*)(s + ABY + rt * 128 +
                                  (((kk << 6) + (l4 << 4)) ^
                                   (((rt >> 2) & 7) << 4)));
      }
#pragma unroll
      for (int m = 0; m < MF; ++m)
#pragma unroll
        for (int n = 0; n < NF; ++n)
          acc[m][n] = __builtin_amdgcn_mfma_f32_16x16x32_bf16(af[m], bfv[n],
                                                              acc[m][n], 0, 0, 0);
    }
    __builtin_amdgcn_sched_barrier(0);
    asm volatile("s_waitcnt lgkmcnt(0)" ::: "memory");
    barrier_mem();
    cur ^= 1;
  }
}

// ACT: 0 none, 1 phi, 2 gelu, 3 phi-if-row<512 (fused k|v)
template <int TM, int TN, int ACT, bool READC, bool PADA, bool PADC,
          bool BIASROW, bool TRIMASK, bool SKIPUP, bool DIVDEN, bool TWOPH,
          bool CONV, bool HALFK>
__device__ __forceinline__ void gemm_body(const GemmP& p, int bm, int bn,
                                          int z, int tid, char* smem) {
  constexpr int MF = TM / 32, NF = TN / 32;
  const int lane = tid & 63, w = tid >> 6;
  const int wr = (w >> 1) * (TM / 2), wc = (w & 1) * (TN / 2);
  const int l15 = lane & 15, l4 = lane >> 4;
  const int cb = bn + wc + l15 * NF;  // lane's first output column

  if (SKIPUP && bn >= bm + TM) {  // fully-masked tile: zero-fill Cb
#pragma unroll
    for (int m = 0; m < MF; ++m)
#pragma unroll
      for (int j = 0; j < 4; ++j) {
        const int rloc = bm + wr + (m << 4) + (l4 << 2) + j;
        const size_t crow = (size_t)p.cZrow * z + rloc;
        if constexpr (NF == 4) {
          uint2 z4{0, 0};
          *(uint2*)&p.Cb[crow * p.ldc + cb] = z4;
        } else {
          *(unsigned*)&p.Cb[crow * p.ldc + cb] = 0;
        }
      }
    return;
  }

  f32x4 acc[MF][NF];
#pragma unroll
  for (int m = 0; m < MF; ++m)
#pragma unroll
    for (int n = 0; n < NF; ++n)
#pragma unroll
      for (int j = 0; j < 4; ++j) acc[m][n][j] = 0.f;

  int arow0 = bm + p.aZrow * z;
  if (PADA) arow0 = bm + ((bm >> 11) << 1);  // padded batch base
  int nkt1 = p.nkt;
  if (HALFK) nkt1 = min(p.nkt, (bm + TM) >> 6);  // causal K truncation
  mma_phase<TM, TN, CONV>(p.A, p.B, nkt1, p.lda, p.ldb, arow0, p.aZcol * z,
                          bn + p.bZrow * z, p.bZcol * z, smem, tid, acc);
  if (TWOPH)
    mma_phase<TM, TN, false>(p.A2, p.B2, p.nkt2, p.lda2, p.ldb2,
                             bm + p.a2Zrow * z, 0, bn + p.b2Zrow * z, 0, smem,
                             tid, acc);

  float bcol[NF];
  if (p.bias && !BIASROW) {
#pragma unroll
    for (int n = 0; n < NF; ++n) bcol[n] = p.bias[cb + n];
  }
  int crow_base = bm;
  if (PADC) crow_base = bm + ((bm >> 11) << 1) + 2;
#pragma unroll
  for (int m = 0; m < MF; ++m) {
#pragma unroll
    for (int j = 0; j < 4; ++j) {
      const int rloc = wr + (m << 4) + (l4 << 2) + j;
      const size_t crow = (size_t)p.cZrow * z + crow_base + rloc;
      float inv = 1.f;
      if (DIVDEN) inv = 1.f / (p.den[crow] + 1e-6f);
      float brbias = 0.f;
      if (BIASROW && p.bias) brbias = p.bias[bm + rloc];
      const size_t cidx0 = crow * p.ldc + cb;
      float oldv[NF];
      if (READC) {
        if constexpr (NF == 4) {
          const uint2 o = *(const uint2*)&p.Cb[cidx0];
          oldv[0] = b2f(o.x & 0xffffu); oldv[1] = b2f(o.x >> 16);
          oldv[2] = b2f(o.y & 0xffffu); oldv[3] = b2f(o.y >> 16);
        } else {
          const unsigned o = *(const unsigned*)&p.Cb[cidx0];
          oldv[0] = b2f(o & 0xffffu); oldv[1] = b2f(o >> 16);
        }
      }
      ushort_t uv[NF];
#pragma unroll
      for (int n = 0; n < NF; ++n) {
        float v = acc[m][n][j];
        if (p.bias) v += BIASROW ? brbias : bcol[n];
        if (ACT == 1) v = v > 0.f ? v + 1.f : __expf(v);
        if (ACT == 2) v = 0.5f * v * (1.f + erff(v * 0.70710678118654752f));
        if (ACT == 3 && (bm + rloc) < 512) v = v > 0.f ? v + 1.f : __expf(v);
        if (TRIMASK) {
          if (cb + n > bm + rloc) v = 0.f;
        }
        if (READC) v += oldv[n];
        if (DIVDEN) v *= inv;
        uv[n] = f2b(v);
      }
      if constexpr (NF == 4) {
        uint2 o;
        o.x = ((unsigned)uv[1] << 16) | uv[0];
        o.y = ((unsigned)uv[3] << 16) | uv[2];
        *(uint2*)&p.Cb[cidx0] = o;
      } else {
        *(unsigned*)&p.Cb[cidx0] = ((unsigned)uv[1] << 16) | uv[0];
      }
    }
  }
}

__device__ __forceinline__ void swz_decode(int r, int gx, int gy, int swz,
                                           int& bx, int& by) {
  if (swz) {
    const int per = gx * gy, cpx = per >> 3;
    const int s = (r & 7) * cpx + (r >> 3);
    if (gx >= gy) { bx = s / gy; by = s % gy; }
    else          { by = s / gx; bx = s % gx; }
  } else {
    bx = r % gx;
    by = r / gx;
  }
}

template <int TM, int TN, int ACT, bool READC, bool PADA, bool PADC,
          bool BIASROW, bool TRIMASK, bool SKIPUP, bool DIVDEN, bool TWOPH,
          bool CONV, bool SWZ, bool HALFK>
__global__ __launch_bounds__(256) void gemm_mfma(GemmP p) {
  __shared__ __align__(16) char smem[2 * (TM + TN) * 128];
  int bxx = blockIdx.x, byy = blockIdx.y;
  if (SWZ) {
    const int gx = gridDim.x, gy = gridDim.y;
    swz_decode(byy * gx + bxx, gx, gy, 1, bxx, byy);
  }
  gemm_body<TM, TN, ACT, READC, PADA, PADC, BIASROW, TRIMASK, SKIPUP, DIVDEN,
            TWOPH, CONV, HALFK>(p, bxx * TM, byy * TN, blockIdx.z, threadIdx.x,
                                smem);
}

// ======================= small phase bodies =======================

__device__ __forceinline__ void ksum_body(const ushort_t* __restrict__ kT,
                                          float* __restrict__ ks, int unit,
                                          int nunits, int tid) {
  const int wid = tid >> 6, lane = tid & 63;
  const int nw = nunits << 2;
  for (int it = (unit << 2) + wid; it < B_SZ * 7 * E_DIM; it += nw) {
    const int zi = it >> 9, e = it & 511;
    const int z = ((zi / 7) << 3) + zi % 7;
    const uint2 u =
        *(const uint2*)(kT + (size_t)e * ROWS + (z << 8) + (lane << 2));
    float s = b2f(u.x & 0xffffu) + b2f(u.x >> 16) + b2f(u.y & 0xffffu) +
              b2f(u.y >> 16);
#pragma unroll
    for (int off = 32; off; off >>= 1) s += __shfl_xor(s, off);
    if (lane == 0) ks[(z << 9) + e] = s;
  }
}

// ============ mega kernels: template-specialized multi-GEMM launches ========

// qk (128x128, ACT=phi, swz grid 64x8) || kvT (128x128, ACT=3, BIASROW, 8x64)
__global__ __launch_bounds__(256) void mega_qkv(GemmP pa, GemmP pb) {
  __shared__ __align__(16) char smem[65536];
  const int tid = threadIdx.x;
  const int bid = blockIdx.x;
  if (bid < 512) {
    int bx, by;
    swz_decode(bid, 64, 8, 1, bx, by);
    gemm_body<128, 128, 1, 0, 0, 0, 0, 0, 0, 0, 0, 0, 0>(pa, bx << 7, by << 7,
                                                          0, tid, smem);
  } else {
    int bx, by;
    swz_decode(bid - 512, 8, 64, 1, bx, by);
    gemm_body<128, 128, 3, 0, 0, 0, 1, 0, 0, 0, 0, 0, 0>(pb, bx << 7, by << 7,
                                                          0, tid, smem);
  }
}

// P (128x128, z in 28 chunks) || Sc (128x64, TRIMASK+SKIPUP) || ksum tail
__global__ __launch_bounds__(256) void mega_psck(GemmP pp, GemmP ps,
                                                 const ushort_t* kT,
                                                 float* ks) {
  __shared__ __align__(16) char smem[65536];
  const int tid = threadIdx.x;
  const int bid = blockIdx.x;
  if (bid < 448) {  // P-GEMM, chunk-7 skipped
    int z = bid >> 4;
    z = (z / 7) * 8 + z % 7;
    const int r = bid & 15;
    gemm_body<128, 128, 0, 0, 0, 0, 0, 0, 0, 0, 0, 0, 0>(
        pp, (r & 3) << 7, (r >> 2) << 7, z, tid, smem);
  } else if (bid < 704) {  // intra-chunk scores
    const int v = bid - 448;
    const int z = v >> 3, r = v & 7;
    gemm_body<128, 64, 0, 0, 0, 0, 0, 1, 1, 0, 0, 0, 0>(
        ps, (r & 1) << 7, (r >> 1) << 6, z, tid, smem);
  } else {
    ksum_body(kT, ks, bid - 704, 256, tid);
  }
}

// ======================= prep kernel (vectorized, + transpose tail) =========

struct CvtP {
  const float *in_W, *cc_W, *Wq, *Wk, *Wv, *Wo, *c1W, *c2W, *bq, *bk, *bv;
  ushort_t *winb, *wconv, *wqkb, *wkvb, *wob, *wc1, *wc2;
  float *bqk, *bkv;
  ushort_t* t2pad;
  const float* x; ushort_t* xT;
};

__device__ __forceinline__ void cvt8(const float* s, ushort_t* d) {
  const float4 a = *(const float4*)s;
  const float4 b = *(const float4*)(s + 4);
  uint4 o;
  o.x = ((unsigned)f2b(a.y) << 16) | f2b(a.x);
  o.y = ((unsigned)f2b(a.w) << 16) | f2b(a.z);
  o.z = ((unsigned)f2b(b.y) << 16) | f2b(b.x);
  o.w = ((unsigned)f2b(b.w) << 16) | f2b(b.z);
  *(uint4*)d = o;
}

#define NB_CVT 2048
__global__ __launch_bounds__(256) void cvt_all(CvtP c) {
  __shared__ float t[64][65];
  const int tid = threadIdx.x;
  if (blockIdx.x >= NB_CVT) {  // transpose_x tail: 128 blocks
    const int v = blockIdx.x - NB_CVT;  // 0..127
    const int b = v >> 5, s0 = (v & 31) << 6;
#pragma unroll
    for (int i = 0; i < 16; ++i) {
      int idx = tid + (i << 8);
      int ch = idx >> 6, s = idx & 63;
      t[ch][s] = c.x[(((size_t)(b * CIN_D + ch)) << 11) + s0 + s];
    }
    __syncthreads();
#pragma unroll
    for (int i = 0; i < 16; ++i) {
      int idx = tid + (i << 8);
      int s = idx >> 6, ch = idx & 63;
      c.xT[(((size_t)(b * S_LEN + s0 + s)) << 6) + ch] = f2b(t[ch][s]);
    }
    return;
  }
  // vectorized conversion: units of 8 elements; all section sizes are 8-aligned
  const size_t NU = (32768 + 786432 + 2097152 * 2 + 1048576 * 3 + 4096 * 2 +
                     4096) >> 3;
  for (size_t iu = (size_t)blockIdx.x * 256 + tid; iu < NU;
       iu += (size_t)NB_CVT * 256) {
    size_t j = iu << 3;
    if (j < 32768) { cvt8(c.in_W + j, c.winb + j); continue; }
    j -= 32768;
    if (j < 786432) {  // wconv[n][tap*512+k] = cc_W[n][k][tap], stride-3 gather
      size_t n = j / 1536, r = j % 1536;
      const float* src = c.cc_W + n * 1536 + (r & 511) * 3 + (r >> 9);
      float v[8];
#pragma unroll
      for (int tS = 0; tS < 8; ++tS) v[tS] = src[tS * 3];
      uint4 o;
      o.x = ((unsigned)f2b(v[1]) << 16) | f2b(v[0]);
      o.y = ((unsigned)f2b(v[3]) << 16) | f2b(v[2]);
      o.z = ((unsigned)f2b(v[5]) << 16) | f2b(v[4]);
      o.w = ((unsigned)f2b(v[7]) << 16) | f2b(v[6]);
      *(uint4*)(c.wconv + j) = o;
      continue;
    }
    j -= 786432;
    if (j < 2097152) {  // wqkb = [Wq;Wk]
      size_t l = j >> 19, r = j & 524287, row = r >> 9, k = r & 511;
      const float* src = row < 512
                             ? c.Wq + l * 262144 + row * 512 + k
                             : c.Wk + l * 262144 + (row - 512) * 512 + k;
      cvt8(src, c.wqkb + j);
      continue;
    }
    j -= 2097152;
    if (j < 2097152) {  // wkvb = [Wk;Wv]
      size_t l = j >> 19, r = j & 524287, row = r >> 9, k = r & 511;
      const float* src = row < 512
                             ? c.Wk + l * 262144 + row * 512 + k
                             : c.Wv + l * 262144 + (row - 512) * 512 + k;
      cvt8(src, c.wkvb + j);
      continue;
    }
    j -= 2097152;
    if (j < 1048576) { cvt8(c.Wo + j, c.wob + j); continue; }
    j -= 1048576;
    if (j < 1048576) { cvt8(c.c1W + j, c.wc1 + j); continue; }
    j -= 1048576;
    if (j < 1048576) { cvt8(c.c2W + j, c.wc2 + j); continue; }
    j -= 1048576;
    if (j < 4096) {  // bqk floats
      size_t l = j >> 10, r = j & 1023;
      const float* src = r < 512 ? c.bq + l * 512 + r : c.bk + l * 512 + r - 512;
      *(float4*)(c.bqk + j) = *(const float4*)src;
      *(float4*)(c.bqk + j + 4) = *(const float4*)(src + 4);
      continue;
    }
    j -= 4096;
    if (j < 4096) {  // bkv floats
      size_t l = j >> 10, r = j & 1023;
      const float* src = r < 512 ? c.bk + l * 512 + r : c.bv + l * 512 + r - 512;
      *(float4*)(c.bkv + j) = *(const float4*)src;
      *(float4*)(c.bkv + j + 4) = *(const float4*)(src + 4);
      continue;
    }
    j -= 4096;
    {  // zero-fill the 2 pad rows at each batch start of t2pad
      int b = (int)(j >> 10), r = (int)(j & 1023);
      uint4 z4{0, 0, 0, 0};
      *(uint4*)(c.t2pad + (size_t)(b * PADR) * E_DIM + r) = z4;
    }
  }
}

// wave-per-row layernorm over bf16 latent: 4 rows / block
__global__ __launch_bounds__(256) void layernorm_b(const ushort_t* __restrict__ x,
                                                   const float* __restrict__ g,
                                                   const float* __restrict__ bb,
                                                   ushort_t* __restrict__ y) {
  const int wid = threadIdx.x >> 6, lane = threadIdx.x & 63;
  const int row = (blockIdx.x << 2) + wid;
  const ushort_t* xr = x + ((size_t)row << 9);
  const uint4 u = *(const uint4*)(xr + (lane << 3));  // 8 bf16
  float v[8];
  v[0] = b2f(u.x & 0xffffu); v[1] = b2f(u.x >> 16);
  v[2] = b2f(u.y & 0xffffu); v[3] = b2f(u.y >> 16);
  v[4] = b2f(u.z & 0xffffu); v[5] = b2f(u.z >> 16);
  v[6] = b2f(u.w & 0xffffu); v[7] = b2f(u.w >> 16);
  float s = 0.f, q2 = 0.f;
#pragma unroll
  for (int i = 0; i < 8; ++i) { s += v[i]; q2 += v[i] * v[i]; }
#pragma unroll
  for (int off = 32; off; off >>= 1) {
    s += __shfl_xor(s, off);
    q2 += __shfl_xor(q2, off);
  }
  const float m = s * (1.f / 512.f);
  const float r = rsqrtf(q2 * (1.f / 512.f) - m * m + 1e-5f);
  const int c = lane << 3;
  const float4 g0 = *(const float4*)(g + c);
  const float4 g1 = *(const float4*)(g + c + 4);
  const float4 b0 = *(const float4*)(bb + c);
  const float4 b1 = *(const float4*)(bb + c + 4);
  uint4 o;
  o.x = ((unsigned)f2b((v[1] - m) * r * g0.y + b0.y) << 16) |
        f2b((v[0] - m) * r * g0.x + b0.x);
  o.y = ((unsigned)f2b((v[3] - m) * r * g0.w + b0.w) << 16) |
        f2b((v[2] - m) * r * g0.z + b0.z);
  o.z = ((unsigned)f2b((v[5] - m) * r * g1.y + b1.y) << 16) |
        f2b((v[4] - m) * r * g1.x + b1.x);
  o.w = ((unsigned)f2b((v[7] - m) * r * g1.w + b1.w) << 16) |
        f2b((v[6] - m) * r * g1.z + b1.z);
  *(uint4*)(y + ((size_t)row << 9) + c) = o;
}

// merged: blocks 0..4095 = exclusive chunk prefix Pb->PTb (bf16, fp32 acc;
//         chunk-7 Pb never computed -> skipped);
//         blocks 4096..6143 = den (wave per row, ks prefix inlined)
__global__ __launch_bounds__(256) void misc_k(
    const ushort_t* __restrict__ Pb, ushort_t* __restrict__ PTb,
    const ushort_t* __restrict__ Sc, const ushort_t* __restrict__ qk,
    const float* __restrict__ ksum, float* __restrict__ den) {
  int bid = blockIdx.x;
  if (bid < 4096) {
    const size_t idx = ((size_t)bid << 8) + threadIdx.x;  // < B*E*E
    const int b = (int)(idx >> 18);
    const size_t r = idx & ((1u << 18) - 1);
    float acc = 0.f;
#pragma unroll
    for (int j = 0; j < NCHK; ++j) {
      const size_t o = (((size_t)(b * NCHK + j)) << 18) + r;
      PTb[o] = f2b(acc);
      if (j < NCHK - 1) acc += b2f(Pb[o]);
    }
  } else {
    bid -= 4096;
    const int wid = threadIdx.x >> 6, lane = threadIdx.x & 63;
    const int row = (bid << 2) + wid;  // < 8192
    const int z = row >> 8, sl = row & 255;
    const ushort_t* sr = Sc + (((size_t)z) << 16) + ((size_t)sl << 8);
    float s = 0.f;
#pragma unroll
    for (int t = 0; t < 4; ++t) s += b2f(sr[lane + (t << 6)]);
    const ushort_t* qr = qk + (size_t)row * QLD;
    const int j0 = z & ~7;
    for (int e = lane; e < E_DIM; e += 64) {
      float kp = 0.f;
      for (int j = j0; j < z; ++j) kp += ksum[(j << 9) + e];
      s += b2f(qr[e]) * kp;
    }
#pragma unroll
    for (int off = 32; off; off >>= 1) s += __shfl_xor(s, off);
    if (lane == 0) den[row] = s;
  }
}

__global__ __launch_bounds__(256) void out_proj(const ushort_t* __restrict__ lat,
                                                const float* __restrict__ W,
                                                const float* __restrict__ bias,
                                                float* __restrict__ out) {
  const int b = blockIdx.z, bs = blockIdx.x << 6;
  const int tid = threadIdx.x, tm = tid >> 4, tn = tid & 15;
  const int lr = tid >> 2, lc = (tid & 3) << 2;
  __shared__ float As[16][64], Ws[16][64];
  float acc[4][4] = {{0.f}};
  for (int k0 = 0; k0 < E_DIM; k0 += 16) {
    const uint2 ra =
        *(const uint2*)(lat + (((size_t)(b * S_LEN + bs + lr)) << 9) + k0 + lc);
    As[lc + 0][lr] = b2f(ra.x & 0xffffu);
    As[lc + 1][lr] = b2f(ra.x >> 16);
    As[lc + 2][lr] = b2f(ra.y & 0xffffu);
    As[lc + 3][lr] = b2f(ra.y >> 16);
    float4 wv = *(const float4*)(W + (((size_t)lr) << 9) + k0 + lc);
    Ws[lc + 0][lr] = wv.x; Ws[lc + 1][lr] = wv.y;
    Ws[lc + 2][lr] = wv.z; Ws[lc + 3][lr] = wv.w;
    __syncthreads();
#pragma unroll
    for (int kk = 0; kk < 16; ++kk) {
      const float4 a4 = *(const float4*)&As[kk][tm << 2];
      const float4 b4 = *(const float4*)&Ws[kk][tn << 2];
      const float aa[4] = {a4.x, a4.y, a4.z, a4.w};
      const float bb[4] = {b4.x, b4.y, b4.z, b4.w};
#pragma unroll
      for (int i = 0; i < 4; ++i)
#pragma unroll
        for (int j2 = 0; j2 < 4; ++j2) acc[i][j2] += aa[i] * bb[j2];
    }
    __syncthreads();
  }
#pragma unroll
  for (int i = 0; i < 4; ++i)
#pragma unroll
    for (int j2 = 0; j2 < 4; ++j2) {
      const int o = (tn << 2) + j2, sl = bs + (tm << 2) + i;
      out[(((size_t)(b * COUT_D + o)) << 11) + sl] = acc[i][j2] + bias[o];
    }
}

// ======================= host launcher =======================
extern "C" void kernel_launch(void* const* d_in, const int* in_sizes, int n_in,
                              void* d_out, int out_size, void* d_ws,
                              size_t ws_size, hipStream_t stream) {
  const float* x = (const float*)d_in[0];
  const float* in_W = (const float*)d_in[1];
  const float* in_b = (const float*)d_in[2];
  const float* cc_W = (const float*)d_in[3];
  const float* cc_b = (const float*)d_in[4];
  const float* ln1g = (const float*)d_in[5];
  const float* ln1b = (const float*)d_in[6];
  const float* ln2g = (const float*)d_in[7];
  const float* ln2b = (const float*)d_in[8];
  const float* Wq = (const float*)d_in[9];
  const float* bq = (const float*)d_in[10];
  const float* Wk = (const float*)d_in[11];
  const float* bk = (const float*)d_in[12];
  const float* Wv = (const float*)d_in[13];
  const float* bv = (const float*)d_in[14];
  const float* Wo = (const float*)d_in[15];
  const float* bo = (const float*)d_in[16];
  const float* c1W = (const float*)d_in[17];
  const float* c1b = (const float*)d_in[18];
  const float* c2W = (const float*)d_in[19];
  const float* c2b = (const float*)d_in[20];
  const float* oW = (const float*)d_in[21];
  const float* ob = (const float*)d_in[22];
  float* out = (float*)d_out;

  const size_t NE = (size_t)ROWS * E_DIM;  // 4194304
  float* ks = (float*)d_ws;  // 16384
  float* den = ks + 16384;   // 8192
  float* bqk = den + 8192;   // 4096
  float* bkv = bqk + 4096;   // 4096
  ushort_t* u = (ushort_t*)(bkv + 4096);
  ushort_t* latb = u;   u += NE;
  ushort_t* Pb = u;     u += 8388608;
  ushort_t* xT = u;     u += (size_t)ROWS * CIN_D;
  ushort_t* t2pad = u;  u += (size_t)B_SZ * PADR * E_DIM;
  ushort_t* h = u;      u += NE;
  ushort_t* qk = u;     u += (size_t)ROWS * QLD;
  ushort_t* kvT = u;    u += (size_t)1024 * ROWS;
  ushort_t* PTb = u;    u += 8388608;
  ushort_t* t2b = u;    u += NE;
  ushort_t* winb = u;   u += 32768;
  ushort_t* wconv = u;  u += 786432;
  ushort_t* wqkb = u;   u += 2097152;
  ushort_t* wkvb = u;   u += 2097152;
  ushort_t* wob = u;    u += 1048576;
  ushort_t* wc1 = u;    u += 1048576;
  ushort_t* wc2 = u;    u += 1048576;
  ushort_t* Sc = t2pad;  // alias: t2pad dead after conv
  ushort_t* kT = kvT;
  ushort_t* vT = kvT + (size_t)512 * ROWS;

  const dim3 blk(256);

  CvtP cp{in_W, cc_W, Wq, Wk, Wv, Wo, c1W, c2W, bq, bk, bv,
          winb, wconv, wqkb, wkvb, wob, wc1, wc2, bqk, bkv, t2pad, x, xT};
  cvt_all<<<dim3(NB_CVT + 128), blk, 0, stream>>>(cp);

  GemmP p;
  auto clr = [&]() {
    p = GemmP{};
    p.lda = E_DIM; p.ldb = E_DIM; p.ldc = E_DIM;
  };

  // template args: TM,TN,ACT,READC,PADA,PADC,BIASROW,TRIMASK,SKIPUP,DIVDEN,
  //                TWOPH,CONV,SWZ,HALFK
  // input projection -> padded bf16 latent (K=64)
  clr(); p.A = xT; p.B = winb; p.bias = in_b; p.Cb = t2pad;
  p.nkt = 1; p.lda = 64; p.ldb = 64;
  gemm_mfma<128,128,0,0,0,1,0,0,0,0,0,0,1,0><<<dim3(64,4), blk, 0, stream>>>(p);
  // fused causal conv: one GEMM, K=1536 (3 taps x 512) -> latb (bf16)
  clr(); p.A = t2pad; p.B = wconv; p.bias = cc_b; p.Cb = latb;
  p.nkt = 24; p.ldb = 1536;
  gemm_mfma<128,128,0,0,1,0,0,0,0,0,0,1,1,0><<<dim3(64,4), blk, 0, stream>>>(p);

  for (int i = 0; i < L_NUM; ++i) {
    const size_t wOff = (size_t)i * E_DIM * E_DIM;
    const size_t bOff = (size_t)i * E_DIM;
    layernorm_b<<<dim3(ROWS / 4), blk, 0, stream>>>(latb, ln1g + bOff,
                                                    ln1b + bOff, h);
    // MEGA: fused q|k GEMM || fused kT|vT GEMM (template-specialized)
    GemmP pa{}; pa.lda = E_DIM; pa.ldb = E_DIM;
    pa.A = h; pa.B = wqkb + (size_t)i * 524288; pa.bias = bqk + i * 1024;
    pa.Cb = qk; pa.nkt = 8; pa.ldc = QLD;
    GemmP pb{}; pb.lda = E_DIM; pb.ldb = E_DIM;
    pb.A = wkvb + (size_t)i * 524288; pb.B = h; pb.bias = bkv + i * 1024;
    pb.Cb = kvT; pb.nkt = 8; pb.ldc = ROWS;
    mega_qkv<<<dim3(1024), blk, 0, stream>>>(pa, pb);
    // MEGA: chunk-KV P (chunk-7 skipped) || intra-chunk Sc || ksum tail
    GemmP pp{};
    pp.A = vT; pp.B = kT; pp.Cb = Pb; pp.nkt = 4;
    pp.lda = ROWS; pp.ldb = ROWS; pp.ldc = E_DIM;
    pp.aZcol = CHK; pp.bZcol = CHK; pp.cZrow = E_DIM;
    GemmP ps{};
    ps.A = qk; ps.B = qk + 512; ps.Cb = Sc; ps.nkt = 8;
    ps.lda = QLD; ps.ldb = QLD; ps.ldc = CHK;
    ps.aZrow = CHK; ps.bZrow = CHK; ps.cZrow = CHK;
    mega_psck<<<dim3(960), blk, 0, stream>>>(pp, ps, kT, ks);
    // merged: prefix (Pb->PTb) || den (rowsum(Sc) + q . inline-ks-prefix)
    misc_k<<<dim3(6144), blk, 0, stream>>>(Pb, PTb, Sc, qk, ks, den);
    // combine: (Sc@vT + q@PTb) / den -> t2b (bf16); causal K-trunc on Sc phase
    clr(); p.A = Sc; p.B = vT; p.Cb = t2b; p.den = den;
    p.nkt = 4; p.lda = CHK; p.ldb = ROWS; p.aZrow = CHK; p.bZcol = CHK;
    p.cZrow = CHK;
    p.A2 = qk; p.B2 = PTb; p.nkt2 = 8; p.lda2 = QLD; p.ldb2 = E_DIM;
    p.a2Zrow = CHK; p.b2Zrow = E_DIM;
    gemm_mfma<64,128,0,0,0,0,0,0,0,1,1,0,0,1><<<dim3(4,4,B_SZ*NCHK), blk, 0, stream>>>(p);
    // latb += t2b @ Wo^T  (bf16 residual RMW)
    clr(); p.A = t2b; p.B = wob + wOff; p.bias = bo + bOff; p.Cb = latb;
    p.nkt = 8;
    gemm_mfma<64,128,0,1,0,0,0,0,0,0,0,0,1,0><<<dim3(128,4), blk, 0, stream>>>(p);
    layernorm_b<<<dim3(ROWS / 4), blk, 0, stream>>>(latb, ln2g + bOff,
                                                    ln2b + bOff, h);
    // c1 (gelu) -> t2b ; latb += t2b @ c2^T
    clr(); p.A = h; p.B = wc1 + wOff; p.bias = c1b + bOff; p.Cb = t2b;
    p.nkt = 8;
    gemm_mfma<64,128,2,0,0,0,0,0,0,0,0,0,1,0><<<dim3(128,4), blk, 0, stream>>>(p);
    clr(); p.A = t2b; p.B = wc2 + wOff; p.bias = c2b + bOff; p.Cb = latb;
    p.nkt = 8;
    gemm_mfma<64,128,0,1,0,0,0,0,0,0,0,0,1,0><<<dim3(128,4), blk, 0, stream>>>(p);
  }
  out_proj<<<dim3(S_LEN / 64, 1, B_SZ), blk, 0, stream>>>(latb, oW, ob, out);
}

// Round 14
// 539.059 us; speedup vs baseline: 1.3339x; 1.0952x over previous
//
#include <hip/hip_runtime.h>
#include <hip/hip_bf16.h>
#include <cmath>

#define S_LEN 2048
#define E_DIM 512
#define B_SZ 4
#define CIN_D 64
#define COUT_D 64
#define L_NUM 4
#define CHK 256
#define NCHK 8
#define ROWS (B_SZ * S_LEN)  // 8192
#define PADR 2050            // padded rows per batch for causal conv
#define QLD 1024             // leading dim of fused qk buffer

typedef __attribute__((ext_vector_type(8))) short short8;
typedef __attribute__((ext_vector_type(4))) float f32x4;
typedef unsigned short ushort_t;

__device__ __forceinline__ ushort_t f2b(float v) {
  __hip_bfloat16 t = __float2bfloat16(v);
  return __builtin_bit_cast(ushort_t, t);
}
__device__ __forceinline__ float b2f(ushort_t u) {
  return __builtin_bit_cast(float, ((unsigned)u) << 16);
}
__device__ __forceinline__ float b2f(unsigned u) {
  return __builtin_bit_cast(float, u << 16);
}

__device__ __forceinline__ void gload16(const void* g, void* l) {
  __builtin_amdgcn_global_load_lds((const __attribute__((address_space(1))) void*)g,
                                   (__attribute__((address_space(3))) void*)l, 16, 0, 0);
}

__device__ __forceinline__ void barrier_mem() {
  asm volatile("s_barrier" ::: "memory");
}
template <int N>
__device__ __forceinline__ void waitn() {
  if constexpr (N == 0) asm volatile("s_waitcnt vmcnt(0)" ::: "memory");
  else if constexpr (N == 6) asm volatile("s_waitcnt vmcnt(6)" ::: "memory");
  else asm volatile("s_waitcnt vmcnt(8)" ::: "memory");
  __builtin_amdgcn_sched_barrier(0);
}

// ======================= universal bf16 MFMA GEMM =======================
// B-fragment n maps lane l15 -> LDS row (wc + l15*NF + n) so each lane's NF
// output columns are CONSECUTIVE -> vectorized (packed bf16) epilogue.
struct GemmP {
  const ushort_t* A; const ushort_t* B; const float* bias;
  ushort_t* Cb; const float* den;
  int nkt, lda, ldb, ldc;
  int aZrow, aZcol, bZrow, bZcol, cZrow;
  const ushort_t* A2; const ushort_t* B2;
  int nkt2, lda2, ldb2, a2Zrow, b2Zrow;
};

template <int TM, int TN, bool CONV>
__device__ __forceinline__ void mma_phase(const ushort_t* A, const ushort_t* B,
                                          int nkt, int lda, int ldb, int arow0,
                                          int acol0, int brow0, int bcol0,
                                          char* sm, int tid,
                                          f32x4 (&acc)[TM / 32][TN / 32]) {
  constexpr int MF = TM / 32, NF = TN / 32;
  constexpr int ABY = TM * 128, BBY = TN * 128, BUF = ABY + BBY;
  constexpr int RA = ABY / 4096, RB = BBY / 4096;
  const int lane = tid & 63, w = tid >> 6;
  const int wr = (w >> 1) * (TM / 2), wc = (w & 1) * (TN / 2);
  const int l15 = lane & 15, l4 = lane >> 4;

  auto stage = [&](int kt, int buf) {
    int ar0 = arow0, ac0 = acol0 + (kt << 6);
    if (CONV) {
      ar0 = arow0 + (kt >> 3);
      ac0 = acol0 + ((kt & 7) << 6);
    }
    char* s = sm + buf * BUF;
#pragma unroll
    for (int r = 0; r < RA; ++r) {
      const int f = (r << 12) + (tid << 4);
      const int row = f >> 7, sw = ((((f >> 4) & 7)) ^ (row & 7)) << 3;
      gload16(A + (size_t)(ar0 + row) * lda + ac0 + sw, s + f);
    }
    const int bc0 = bcol0 + (kt << 6);
#pragma unroll
    for (int r = 0; r < RB; ++r) {
      const int f = (r << 12) + (tid << 4);
      const int row = f >> 7, sw = ((((f >> 4) & 7)) ^ ((row >> 2) & 7)) << 3;
      gload16(B + (size_t)(brow0 + row) * ldb + bc0 + sw, s + ABY + f);
    }
  };

  stage(0, 0);
  int cur = 0;
  for (int kt = 0; kt < nkt; ++kt) {
    if (kt + 1 < nkt) {
      stage(kt + 1, cur ^ 1);  // prefetch next tile
      waitn<RA + RB>();        // wait ONLY the older (current) tile
    } else {
      waitn<0>();
    }
    barrier_mem();
    char* s = sm + cur * BUF;
#pragma unroll
    for (int kk = 0; kk < 2; ++kk) {
      short8 af[MF], bfv[NF];
#pragma unroll
      for (int m = 0; m < MF; ++m) {
        const int rt = wr + (m << 4) + l15;
        af[m] = *(const short8*)(s + rt * 128 +
                                 (((kk << 6) + (l4 << 4)) ^ ((rt & 7) << 4)));
      }
#pragma unroll
      for (int n = 0; n < NF; ++n) {
        const int rt = wc + l15 * NF + n;
        bfv[n] = *(const short8*)(s + ABY + rt * 128 +
                                  (((kk << 6) + (l4 << 4)) ^
                                   (((rt >> 2) & 7) << 4)));
      }
#pragma unroll
      for (int m = 0; m < MF; ++m)
#pragma unroll
        for (int n = 0; n < NF; ++n)
          acc[m][n] = __builtin_amdgcn_mfma_f32_16x16x32_bf16(af[m], bfv[n],
                                                              acc[m][n], 0, 0, 0);
    }
    __builtin_amdgcn_sched_barrier(0);
    asm volatile("s_waitcnt lgkmcnt(0)" ::: "memory");
    barrier_mem();
    cur ^= 1;
  }
}

// ACT: 0 none, 1 phi, 2 gelu, 3 phi-if-row<512 (fused k|v)
template <int TM, int TN, int ACT, bool READC, bool PADA, bool PADC,
          bool BIASROW, bool TRIMASK, bool SKIPUP, bool DIVDEN, bool TWOPH,
          bool CONV, bool HALFK>
__device__ __forceinline__ void gemm_body(const GemmP& p, int bm, int bn,
                                          int z, int tid, char* smem) {
  constexpr int MF = TM / 32, NF = TN / 32;
  const int lane = tid & 63, w = tid >> 6;
  const int wr = (w >> 1) * (TM / 2), wc = (w & 1) * (TN / 2);
  const int l15 = lane & 15, l4 = lane >> 4;
  const int cb = bn + wc + l15 * NF;  // lane's first output column

  if (SKIPUP && bn >= bm + TM) {  // fully-masked tile: zero-fill Cb
#pragma unroll
    for (int m = 0; m < MF; ++m)
#pragma unroll
      for (int j = 0; j < 4; ++j) {
        const int rloc = bm + wr + (m << 4) + (l4 << 2) + j;
        const size_t crow = (size_t)p.cZrow * z + rloc;
        if constexpr (NF == 4) {
          uint2 z4{0, 0};
          *(uint2*)&p.Cb[crow * p.ldc + cb] = z4;
        } else {
          *(unsigned*)&p.Cb[crow * p.ldc + cb] = 0;
        }
      }
    return;
  }

  f32x4 acc[MF][NF];
#pragma unroll
  for (int m = 0; m < MF; ++m)
#pragma unroll
    for (int n = 0; n < NF; ++n)
#pragma unroll
      for (int j = 0; j < 4; ++j) acc[m][n][j] = 0.f;

  int arow0 = bm + p.aZrow * z;
  if (PADA) arow0 = bm + ((bm >> 11) << 1);  // padded batch base
  int nkt1 = p.nkt;
  if (HALFK) nkt1 = min(p.nkt, (bm + TM) >> 6);  // causal K truncation
  mma_phase<TM, TN, CONV>(p.A, p.B, nkt1, p.lda, p.ldb, arow0, p.aZcol * z,
                          bn + p.bZrow * z, p.bZcol * z, smem, tid, acc);
  if (TWOPH)
    mma_phase<TM, TN, false>(p.A2, p.B2, p.nkt2, p.lda2, p.ldb2,
                             bm + p.a2Zrow * z, 0, bn + p.b2Zrow * z, 0, smem,
                             tid, acc);

  float bcol[NF];
  if (p.bias && !BIASROW) {
#pragma unroll
    for (int n = 0; n < NF; ++n) bcol[n] = p.bias[cb + n];
  }
  int crow_base = bm;
  if (PADC) crow_base = bm + ((bm >> 11) << 1) + 2;
#pragma unroll
  for (int m = 0; m < MF; ++m) {
#pragma unroll
    for (int j = 0; j < 4; ++j) {
      const int rloc = wr + (m << 4) + (l4 << 2) + j;
      const size_t crow = (size_t)p.cZrow * z + crow_base + rloc;
      float inv = 1.f;
      if (DIVDEN) inv = 1.f / (p.den[crow] + 1e-6f);
      float brbias = 0.f;
      if (BIASROW && p.bias) brbias = p.bias[bm + rloc];
      const size_t cidx0 = crow * p.ldc + cb;
      float oldv[NF];
      if (READC) {
        if constexpr (NF == 4) {
          const uint2 o = *(const uint2*)&p.Cb[cidx0];
          oldv[0] = b2f(o.x & 0xffffu); oldv[1] = b2f(o.x >> 16);
          oldv[2] = b2f(o.y & 0xffffu); oldv[3] = b2f(o.y >> 16);
        } else {
          const unsigned o = *(const unsigned*)&p.Cb[cidx0];
          oldv[0] = b2f(o & 0xffffu); oldv[1] = b2f(o >> 16);
        }
      }
      ushort_t uv[NF];
#pragma unroll
      for (int n = 0; n < NF; ++n) {
        float v = acc[m][n][j];
        if (p.bias) v += BIASROW ? brbias : bcol[n];
        if (ACT == 1) v = v > 0.f ? v + 1.f : __expf(v);
        if (ACT == 2) v = 0.5f * v * (1.f + erff(v * 0.70710678118654752f));
        if (ACT == 3 && (bm + rloc) < 512) v = v > 0.f ? v + 1.f : __expf(v);
        if (TRIMASK) {
          if (cb + n > bm + rloc) v = 0.f;
        }
        if (READC) v += oldv[n];
        if (DIVDEN) v *= inv;
        uv[n] = f2b(v);
      }
      if constexpr (NF == 4) {
        uint2 o;
        o.x = ((unsigned)uv[1] << 16) | uv[0];
        o.y = ((unsigned)uv[3] << 16) | uv[2];
        *(uint2*)&p.Cb[cidx0] = o;
      } else {
        *(unsigned*)&p.Cb[cidx0] = ((unsigned)uv[1] << 16) | uv[0];
      }
    }
  }
}

__device__ __forceinline__ void swz_decode(int r, int gx, int gy, int swz,
                                           int& bx, int& by) {
  if (swz) {
    const int per = gx * gy, cpx = per >> 3;
    const int s = (r & 7) * cpx + (r >> 3);
    if (gx >= gy) { bx = s / gy; by = s % gy; }
    else          { by = s / gx; bx = s % gx; }
  } else {
    bx = r % gx;
    by = r / gx;
  }
}

template <int TM, int TN, int ACT, bool READC, bool PADA, bool PADC,
          bool BIASROW, bool TRIMASK, bool SKIPUP, bool DIVDEN, bool TWOPH,
          bool CONV, bool SWZ, bool HALFK>
__global__ __launch_bounds__(256) void gemm_mfma(GemmP p) {
  __shared__ __align__(16) char smem[2 * (TM + TN) * 128];
  int bxx = blockIdx.x, byy = blockIdx.y;
  if (SWZ) {
    const int gx = gridDim.x, gy = gridDim.y;
    swz_decode(byy * gx + bxx, gx, gy, 1, bxx, byy);
  }
  gemm_body<TM, TN, ACT, READC, PADA, PADC, BIASROW, TRIMASK, SKIPUP, DIVDEN,
            TWOPH, CONV, HALFK>(p, bxx * TM, byy * TN, blockIdx.z, threadIdx.x,
                                smem);
}

// ======================= small phase bodies =======================

__device__ __forceinline__ void ksum_body(const ushort_t* __restrict__ kT,
                                          float* __restrict__ ks, int unit,
                                          int nunits, int tid) {
  const int wid = tid >> 6, lane = tid & 63;
  const int nw = nunits << 2;
  for (int it = (unit << 2) + wid; it < B_SZ * 7 * E_DIM; it += nw) {
    const int zi = it >> 9, e = it & 511;
    const int z = ((zi / 7) << 3) + zi % 7;
    const uint2 u =
        *(const uint2*)(kT + (size_t)e * ROWS + (z << 8) + (lane << 2));
    float s = b2f(u.x & 0xffffu) + b2f(u.x >> 16) + b2f(u.y & 0xffffu) +
              b2f(u.y >> 16);
#pragma unroll
    for (int off = 32; off; off >>= 1) s += __shfl_xor(s, off);
    if (lane == 0) ks[(z << 9) + e] = s;
  }
}

// ============ mega kernels: template-specialized multi-GEMM launches ========

// qk (128x128, ACT=phi, swz grid 64x8) || kvT (128x128, ACT=3, BIASROW, 8x64)
__global__ __launch_bounds__(256) void mega_qkv(GemmP pa, GemmP pb) {
  __shared__ __align__(16) char smem[65536];
  const int tid = threadIdx.x;
  const int bid = blockIdx.x;
  if (bid < 512) {
    int bx, by;
    swz_decode(bid, 64, 8, 1, bx, by);
    gemm_body<128, 128, 1, 0, 0, 0, 0, 0, 0, 0, 0, 0, 0>(pa, bx << 7, by << 7,
                                                          0, tid, smem);
  } else {
    int bx, by;
    swz_decode(bid - 512, 8, 64, 1, bx, by);
    gemm_body<128, 128, 3, 0, 0, 0, 1, 0, 0, 0, 0, 0, 0>(pb, bx << 7, by << 7,
                                                          0, tid, smem);
  }
}

// P (128x128, z in 28 chunks) || Sc (128x64, TRIMASK+SKIPUP) || ksum tail
__global__ __launch_bounds__(256) void mega_psck(GemmP pp, GemmP ps,
                                                 const ushort_t* kT,
                                                 float* ks) {
  __shared__ __align__(16) char smem[65536];
  const int tid = threadIdx.x;
  const int bid = blockIdx.x;
  if (bid < 448) {  // P-GEMM, chunk-7 skipped
    int z = bid >> 4;
    z = (z / 7) * 8 + z % 7;
    const int r = bid & 15;
    gemm_body<128, 128, 0, 0, 0, 0, 0, 0, 0, 0, 0, 0, 0>(
        pp, (r & 3) << 7, (r >> 2) << 7, z, tid, smem);
  } else if (bid < 704) {  // intra-chunk scores
    const int v = bid - 448;
    const int z = v >> 3, r = v & 7;
    gemm_body<128, 64, 0, 0, 0, 0, 0, 1, 1, 0, 0, 0, 0>(
        ps, (r & 1) << 7, (r >> 1) << 6, z, tid, smem);
  } else {
    ksum_body(kT, ks, bid - 704, 256, tid);
  }
}

// ======================= prep kernel (vectorized, + transpose tail) =========

struct CvtP {
  const float *in_W, *cc_W, *Wq, *Wk, *Wv, *Wo, *c1W, *c2W, *bq, *bk, *bv;
  ushort_t *winb, *wconv, *wqkb, *wkvb, *wob, *wc1, *wc2;
  float *bqk, *bkv;
  ushort_t* t2pad;
  const float* x; ushort_t* xT;
};

__device__ __forceinline__ void cvt8(const float* s, ushort_t* d) {
  const float4 a = *(const float4*)s;
  const float4 b = *(const float4*)(s + 4);
  uint4 o;
  o.x = ((unsigned)f2b(a.y) << 16) | f2b(a.x);
  o.y = ((unsigned)f2b(a.w) << 16) | f2b(a.z);
  o.z = ((unsigned)f2b(b.y) << 16) | f2b(b.x);
  o.w = ((unsigned)f2b(b.w) << 16) | f2b(b.z);
  *(uint4*)d = o;
}

#define NB_CVT 2048
__global__ __launch_bounds__(256) void cvt_all(CvtP c) {
  __shared__ float t[64][65];
  const int tid = threadIdx.x;
  if (blockIdx.x >= NB_CVT) {  // transpose_x tail: 128 blocks
    const int v = blockIdx.x - NB_CVT;  // 0..127
    const int b = v >> 5, s0 = (v & 31) << 6;
#pragma unroll
    for (int i = 0; i < 16; ++i) {
      int idx = tid + (i << 8);
      int ch = idx >> 6, s = idx & 63;
      t[ch][s] = c.x[(((size_t)(b * CIN_D + ch)) << 11) + s0 + s];
    }
    __syncthreads();
#pragma unroll
    for (int i = 0; i < 16; ++i) {
      int idx = tid + (i << 8);
      int s = idx >> 6, ch = idx & 63;
      c.xT[(((size_t)(b * S_LEN + s0 + s)) << 6) + ch] = f2b(t[ch][s]);
    }
    return;
  }
  // vectorized conversion: units of 8 elements; all section sizes are 8-aligned
  const size_t NU = (32768 + 786432 + 2097152 * 2 + 1048576 * 3 + 4096 * 2 +
                     4096) >> 3;
  for (size_t iu = (size_t)blockIdx.x * 256 + tid; iu < NU;
       iu += (size_t)NB_CVT * 256) {
    size_t j = iu << 3;
    if (j < 32768) { cvt8(c.in_W + j, c.winb + j); continue; }
    j -= 32768;
    if (j < 786432) {  // wconv[n][tap*512+k] = cc_W[n][k][tap], stride-3 gather
      size_t n = j / 1536, r = j % 1536;
      const float* src = c.cc_W + n * 1536 + (r & 511) * 3 + (r >> 9);
      float v[8];
#pragma unroll
      for (int tS = 0; tS < 8; ++tS) v[tS] = src[tS * 3];
      uint4 o;
      o.x = ((unsigned)f2b(v[1]) << 16) | f2b(v[0]);
      o.y = ((unsigned)f2b(v[3]) << 16) | f2b(v[2]);
      o.z = ((unsigned)f2b(v[5]) << 16) | f2b(v[4]);
      o.w = ((unsigned)f2b(v[7]) << 16) | f2b(v[6]);
      *(uint4*)(c.wconv + j) = o;
      continue;
    }
    j -= 786432;
    if (j < 2097152) {  // wqkb = [Wq;Wk]
      size_t l = j >> 19, r = j & 524287, row = r >> 9, k = r & 511;
      const float* src = row < 512
                             ? c.Wq + l * 262144 + row * 512 + k
                             : c.Wk + l * 262144 + (row - 512) * 512 + k;
      cvt8(src, c.wqkb + j);
      continue;
    }
    j -= 2097152;
    if (j < 2097152) {  // wkvb = [Wk;Wv]
      size_t l = j >> 19, r = j & 524287, row = r >> 9, k = r & 511;
      const float* src = row < 512
                             ? c.Wk + l * 262144 + row * 512 + k
                             : c.Wv + l * 262144 + (row - 512) * 512 + k;
      cvt8(src, c.wkvb + j);
      continue;
    }
    j -= 2097152;
    if (j < 1048576) { cvt8(c.Wo + j, c.wob + j); continue; }
    j -= 1048576;
    if (j < 1048576) { cvt8(c.c1W + j, c.wc1 + j); continue; }
    j -= 1048576;
    if (j < 1048576) { cvt8(c.c2W + j, c.wc2 + j); continue; }
    j -= 1048576;
    if (j < 4096) {  // bqk floats
      size_t l = j >> 10, r = j & 1023;
      const float* src = r < 512 ? c.bq + l * 512 + r : c.bk + l * 512 + r - 512;
      *(float4*)(c.bqk + j) = *(const float4*)src;
      *(float4*)(c.bqk + j + 4) = *(const float4*)(src + 4);
      continue;
    }
    j -= 4096;
    if (j < 4096) {  // bkv floats
      size_t l = j >> 10, r = j & 1023;
      const float* src = r < 512 ? c.bk + l * 512 + r : c.bv + l * 512 + r - 512;
      *(float4*)(c.bkv + j) = *(const float4*)src;
      *(float4*)(c.bkv + j + 4) = *(const float4*)(src + 4);
      continue;
    }
    j -= 4096;
    {  // zero-fill the 2 pad rows at each batch start of t2pad
      int b = (int)(j >> 10), r = (int)(j & 1023);
      uint4 z4{0, 0, 0, 0};
      *(uint4*)(c.t2pad + (size_t)(b * PADR) * E_DIM + r) = z4;
    }
  }
}

// wave-per-row layernorm over bf16 latent: 4 rows / block
__global__ __launch_bounds__(256) void layernorm_b(const ushort_t* __restrict__ x,
                                                   const float* __restrict__ g,
                                                   const float* __restrict__ bb,
                                                   ushort_t* __restrict__ y) {
  const int wid = threadIdx.x >> 6, lane = threadIdx.x & 63;
  const int row = (blockIdx.x << 2) + wid;
  const ushort_t* xr = x + ((size_t)row << 9);
  const uint4 u = *(const uint4*)(xr + (lane << 3));  // 8 bf16
  float v[8];
  v[0] = b2f(u.x & 0xffffu); v[1] = b2f(u.x >> 16);
  v[2] = b2f(u.y & 0xffffu); v[3] = b2f(u.y >> 16);
  v[4] = b2f(u.z & 0xffffu); v[5] = b2f(u.z >> 16);
  v[6] = b2f(u.w & 0xffffu); v[7] = b2f(u.w >> 16);
  float s = 0.f, q2 = 0.f;
#pragma unroll
  for (int i = 0; i < 8; ++i) { s += v[i]; q2 += v[i] * v[i]; }
#pragma unroll
  for (int off = 32; off; off >>= 1) {
    s += __shfl_xor(s, off);
    q2 += __shfl_xor(q2, off);
  }
  const float m = s * (1.f / 512.f);
  const float r = rsqrtf(q2 * (1.f / 512.f) - m * m + 1e-5f);
  const int c = lane << 3;
  const float4 g0 = *(const float4*)(g + c);
  const float4 g1 = *(const float4*)(g + c + 4);
  const float4 b0 = *(const float4*)(bb + c);
  const float4 b1 = *(const float4*)(bb + c + 4);
  uint4 o;
  o.x = ((unsigned)f2b((v[1] - m) * r * g0.y + b0.y) << 16) |
        f2b((v[0] - m) * r * g0.x + b0.x);
  o.y = ((unsigned)f2b((v[3] - m) * r * g0.w + b0.w) << 16) |
        f2b((v[2] - m) * r * g0.z + b0.z);
  o.z = ((unsigned)f2b((v[5] - m) * r * g1.y + b1.y) << 16) |
        f2b((v[4] - m) * r * g1.x + b1.x);
  o.w = ((unsigned)f2b((v[7] - m) * r * g1.w + b1.w) << 16) |
        f2b((v[6] - m) * r * g1.z + b1.z);
  *(uint4*)(y + ((size_t)row << 9) + c) = o;
}

// merged: blocks 0..2047 = exclusive chunk prefix Pb->PTb, 2 elems/thread
//         (packed bf16 loads/stores; chunk-7 Pb never computed -> skipped);
//         blocks 2048..4095 = den (wave per row, vectorized, ks prefix inline)
__global__ __launch_bounds__(256) void misc_k(
    const ushort_t* __restrict__ Pb, ushort_t* __restrict__ PTb,
    const ushort_t* __restrict__ Sc, const ushort_t* __restrict__ qk,
    const float* __restrict__ ksum, float* __restrict__ den) {
  int bid = blockIdx.x;
  if (bid < 2048) {
    const size_t idx = ((size_t)bid << 8) + threadIdx.x;  // < B*E*E/2
    const int b = (int)(idx >> 17);
    const size_t r = (idx & ((1u << 17) - 1)) << 1;  // even element index
    float a0 = 0.f, a1 = 0.f;
#pragma unroll
    for (int j = 0; j < NCHK; ++j) {
      const size_t o = (((size_t)(b * NCHK + j)) << 18) + r;
      *(unsigned*)&PTb[o] = ((unsigned)f2b(a1) << 16) | f2b(a0);
      if (j < NCHK - 1) {
        const unsigned u = *(const unsigned*)&Pb[o];
        a0 += b2f(u & 0xffffu);
        a1 += b2f(u >> 16);
      }
    }
  } else {
    bid -= 2048;
    const int wid = threadIdx.x >> 6, lane = threadIdx.x & 63;
    const int row = (bid << 2) + wid;  // < 8192
    const int z = row >> 8, sl = row & 255;
    const ushort_t* sr = Sc + (((size_t)z) << 16) + ((size_t)sl << 8);
    const uint2 s4 = *(const uint2*)(sr + (lane << 2));  // 4 bf16 of Sc row
    float s = b2f(s4.x & 0xffffu) + b2f(s4.x >> 16) + b2f(s4.y & 0xffffu) +
              b2f(s4.y >> 16);
    const ushort_t* qr = qk + (size_t)row * QLD;
    const int j0 = z & ~7;
#pragma unroll
    for (int it = 0; it < 2; ++it) {
      const int e = (lane << 2) + (it << 8);
      const uint2 q4 = *(const uint2*)(qr + e);
      float k0 = 0.f, k1 = 0.f, k2 = 0.f, k3 = 0.f;
      for (int j = j0; j < z; ++j) {
        const float4 kj = *(const float4*)(ksum + (j << 9) + e);
        k0 += kj.x; k1 += kj.y; k2 += kj.z; k3 += kj.w;
      }
      s += b2f(q4.x & 0xffffu) * k0 + b2f(q4.x >> 16) * k1 +
           b2f(q4.y & 0xffffu) * k2 + b2f(q4.y >> 16) * k3;
    }
#pragma unroll
    for (int off = 32; off; off >>= 1) s += __shfl_xor(s, off);
    if (lane == 0) den[row] = s;
  }
}

__global__ __launch_bounds__(256) void out_proj(const ushort_t* __restrict__ lat,
                                                const float* __restrict__ W,
                                                const float* __restrict__ bias,
                                                float* __restrict__ out) {
  const int b = blockIdx.z, bs = blockIdx.x << 6;
  const int tid = threadIdx.x, tm = tid >> 4, tn = tid & 15;
  const int lr = tid >> 2, lc = (tid & 3) << 2;
  __shared__ float As[16][64], Ws[16][64];
  float acc[4][4] = {{0.f}};
  for (int k0 = 0; k0 < E_DIM; k0 += 16) {
    const uint2 ra =
        *(const uint2*)(lat + (((size_t)(b * S_LEN + bs + lr)) << 9) + k0 + lc);
    As[lc + 0][lr] = b2f(ra.x & 0xffffu);
    As[lc + 1][lr] = b2f(ra.x >> 16);
    As[lc + 2][lr] = b2f(ra.y & 0xffffu);
    As[lc + 3][lr] = b2f(ra.y >> 16);
    float4 wv = *(const float4*)(W + (((size_t)lr) << 9) + k0 + lc);
    Ws[lc + 0][lr] = wv.x; Ws[lc + 1][lr] = wv.y;
    Ws[lc + 2][lr] = wv.z; Ws[lc + 3][lr] = wv.w;
    __syncthreads();
#pragma unroll
    for (int kk = 0; kk < 16; ++kk) {
      const float4 a4 = *(const float4*)&As[kk][tm << 2];
      const float4 b4 = *(const float4*)&Ws[kk][tn << 2];
      const float aa[4] = {a4.x, a4.y, a4.z, a4.w};
      const float bb[4] = {b4.x, b4.y, b4.z, b4.w};
#pragma unroll
      for (int i = 0; i < 4; ++i)
#pragma unroll
        for (int j2 = 0; j2 < 4; ++j2) acc[i][j2] += aa[i] * bb[j2];
    }
    __syncthreads();
  }
#pragma unroll
  for (int i = 0; i < 4; ++i)
#pragma unroll
    for (int j2 = 0; j2 < 4; ++j2) {
      const int o = (tn << 2) + j2, sl = bs + (tm << 2) + i;
      out[(((size_t)(b * COUT_D + o)) << 11) + sl] = acc[i][j2] + bias[o];
    }
}

// ======================= host launcher =======================
extern "C" void kernel_launch(void* const* d_in, const int* in_sizes, int n_in,
                              void* d_out, int out_size, void* d_ws,
                              size_t ws_size, hipStream_t stream) {
  const float* x = (const float*)d_in[0];
  const float* in_W = (const float*)d_in[1];
  const float* in_b = (const float*)d_in[2];
  const float* cc_W = (const float*)d_in[3];
  const float* cc_b = (const float*)d_in[4];
  const float* ln1g = (const float*)d_in[5];
  const float* ln1b = (const float*)d_in[6];
  const float* ln2g = (const float*)d_in[7];
  const float* ln2b = (const float*)d_in[8];
  const float* Wq = (const float*)d_in[9];
  const float* bq = (const float*)d_in[10];
  const float* Wk = (const float*)d_in[11];
  const float* bk = (const float*)d_in[12];
  const float* Wv = (const float*)d_in[13];
  const float* bv = (const float*)d_in[14];
  const float* Wo = (const float*)d_in[15];
  const float* bo = (const float*)d_in[16];
  const float* c1W = (const float*)d_in[17];
  const float* c1b = (const float*)d_in[18];
  const float* c2W = (const float*)d_in[19];
  const float* c2b = (const float*)d_in[20];
  const float* oW = (const float*)d_in[21];
  const float* ob = (const float*)d_in[22];
  float* out = (float*)d_out;

  const size_t NE = (size_t)ROWS * E_DIM;  // 4194304
  float* ks = (float*)d_ws;  // 16384
  float* den = ks + 16384;   // 8192
  float* bqk = den + 8192;   // 4096
  float* bkv = bqk + 4096;   // 4096
  ushort_t* u = (ushort_t*)(bkv + 4096);
  ushort_t* latb = u;   u += NE;
  ushort_t* Pb = u;     u += 8388608;
  ushort_t* xT = u;     u += (size_t)ROWS * CIN_D;
  ushort_t* t2pad = u;  u += (size_t)B_SZ * PADR * E_DIM;
  ushort_t* h = u;      u += NE;
  ushort_t* qk = u;     u += (size_t)ROWS * QLD;
  ushort_t* kvT = u;    u += (size_t)1024 * ROWS;
  ushort_t* PTb = u;    u += 8388608;
  ushort_t* t2b = u;    u += NE;
  ushort_t* winb = u;   u += 32768;
  ushort_t* wconv = u;  u += 786432;
  ushort_t* wqkb = u;   u += 2097152;
  ushort_t* wkvb = u;   u += 2097152;
  ushort_t* wob = u;    u += 1048576;
  ushort_t* wc1 = u;    u += 1048576;
  ushort_t* wc2 = u;    u += 1048576;
  ushort_t* Sc = t2pad;  // alias: t2pad dead after conv
  ushort_t* kT = kvT;
  ushort_t* vT = kvT + (size_t)512 * ROWS;

  const dim3 blk(256);

  CvtP cp{in_W, cc_W, Wq, Wk, Wv, Wo, c1W, c2W, bq, bk, bv,
          winb, wconv, wqkb, wkvb, wob, wc1, wc2, bqk, bkv, t2pad, x, xT};
  cvt_all<<<dim3(NB_CVT + 128), blk, 0, stream>>>(cp);

  GemmP p;
  auto clr = [&]() {
    p = GemmP{};
    p.lda = E_DIM; p.ldb = E_DIM; p.ldc = E_DIM;
  };

  // template args: TM,TN,ACT,READC,PADA,PADC,BIASROW,TRIMASK,SKIPUP,DIVDEN,
  //                TWOPH,CONV,SWZ,HALFK
  // input projection -> padded bf16 latent (K=64)
  clr(); p.A = xT; p.B = winb; p.bias = in_b; p.Cb = t2pad;
  p.nkt = 1; p.lda = 64; p.ldb = 64;
  gemm_mfma<128,128,0,0,0,1,0,0,0,0,0,0,1,0><<<dim3(64,4), blk, 0, stream>>>(p);
  // fused causal conv: one GEMM, K=1536 (3 taps x 512) -> latb (bf16)
  clr(); p.A = t2pad; p.B = wconv; p.bias = cc_b; p.Cb = latb;
  p.nkt = 24; p.ldb = 1536;
  gemm_mfma<128,128,0,0,1,0,0,0,0,0,0,1,1,0><<<dim3(64,4), blk, 0, stream>>>(p);

  for (int i = 0; i < L_NUM; ++i) {
    const size_t wOff = (size_t)i * E_DIM * E_DIM;
    const size_t bOff = (size_t)i * E_DIM;
    layernorm_b<<<dim3(ROWS / 4), blk, 0, stream>>>(latb, ln1g + bOff,
                                                    ln1b + bOff, h);
    // MEGA: fused q|k GEMM || fused kT|vT GEMM (template-specialized)
    GemmP pa{}; pa.lda = E_DIM; pa.ldb = E_DIM;
    pa.A = h; pa.B = wqkb + (size_t)i * 524288; pa.bias = bqk + i * 1024;
    pa.Cb = qk; pa.nkt = 8; pa.ldc = QLD;
    GemmP pb{}; pb.lda = E_DIM; pb.ldb = E_DIM;
    pb.A = wkvb + (size_t)i * 524288; pb.B = h; pb.bias = bkv + i * 1024;
    pb.Cb = kvT; pb.nkt = 8; pb.ldc = ROWS;
    mega_qkv<<<dim3(1024), blk, 0, stream>>>(pa, pb);
    // MEGA: chunk-KV P (chunk-7 skipped) || intra-chunk Sc || ksum tail
    GemmP pp{};
    pp.A = vT; pp.B = kT; pp.Cb = Pb; pp.nkt = 4;
    pp.lda = ROWS; pp.ldb = ROWS; pp.ldc = E_DIM;
    pp.aZcol = CHK; pp.bZcol = CHK; pp.cZrow = E_DIM;
    GemmP ps{};
    ps.A = qk; ps.B = qk + 512; ps.Cb = Sc; ps.nkt = 8;
    ps.lda = QLD; ps.ldb = QLD; ps.ldc = CHK;
    ps.aZrow = CHK; ps.bZrow = CHK; ps.cZrow = CHK;
    mega_psck<<<dim3(960), blk, 0, stream>>>(pp, ps, kT, ks);
    // merged: prefix (Pb->PTb, packed) || den (vectorized)
    misc_k<<<dim3(4096), blk, 0, stream>>>(Pb, PTb, Sc, qk, ks, den);
    // combine: (Sc@vT + q@PTb) / den -> t2b (bf16); causal K-trunc on Sc phase
    clr(); p.A = Sc; p.B = vT; p.Cb = t2b; p.den = den;
    p.nkt = 4; p.lda = CHK; p.ldb = ROWS; p.aZrow = CHK; p.bZcol = CHK;
    p.cZrow = CHK;
    p.A2 = qk; p.B2 = PTb; p.nkt2 = 8; p.lda2 = QLD; p.ldb2 = E_DIM;
    p.a2Zrow = CHK; p.b2Zrow = E_DIM;
    gemm_mfma<64,128,0,0,0,0,0,0,0,1,1,0,0,1><<<dim3(4,4,B_SZ*NCHK), blk, 0, stream>>>(p);
    // latb += t2b @ Wo^T  (bf16 residual RMW)
    clr(); p.A = t2b; p.B = wob + wOff; p.bias = bo + bOff; p.Cb = latb;
    p.nkt = 8;
    gemm_mfma<64,128,0,1,0,0,0,0,0,0,0,0,1,0><<<dim3(128,4), blk, 0, stream>>>(p);
    layernorm_b<<<dim3(ROWS / 4), blk, 0, stream>>>(latb, ln2g + bOff,
                                                    ln2b + bOff, h);
    // c1 (gelu) -> t2b ; latb += t2b @ c2^T
    clr(); p.A = h; p.B = wc1 + wOff; p.bias = c1b + bOff; p.Cb = t2b;
    p.nkt = 8;
    gemm_mfma<64,128,2,0,0,0,0,0,0,0,0,0,1,0><<<dim3(128,4), blk, 0, stream>>>(p);
    clr(); p.A = t2b; p.B = wc2 + wOff; p.bias = c2b + bOff; p.Cb = latb;
    p.nkt = 8;
    gemm_mfma<64,128,0,1,0,0,0,0,0,0,0,0,1,0><<<dim3(128,4), blk, 0, stream>>>(p);
  }
  out_proj<<<dim3(S_LEN / 64, 1, B_SZ), blk, 0, stream>>>(latb, oW, ob, out);
}

// Round 15
// 534.303 us; speedup vs baseline: 1.3458x; 1.0089x over previous
//
#include <hip/hip_runtime.h>
#include <hip/hip_bf16.h>
#include <cmath>

#define S_LEN 2048
#define E_DIM 512
#define B_SZ 4
#define CIN_D 64
#define COUT_D 64
#define L_NUM 4
#define CHK 256
#define NCHK 8
#define ROWS (B_SZ * S_LEN)  // 8192
#define PADR 2050            // padded rows per batch for causal conv
#define QLD 1024             // leading dim of fused qk buffer

typedef __attribute__((ext_vector_type(8))) short short8;
typedef __attribute__((ext_vector_type(4))) float f32x4;
typedef unsigned short ushort_t;

__device__ __forceinline__ ushort_t f2b(float v) {
  __hip_bfloat16 t = __float2bfloat16(v);
  return __builtin_bit_cast(ushort_t, t);
}
__device__ __forceinline__ float b2f(ushort_t u) {
  return __builtin_bit_cast(float, ((unsigned)u) << 16);
}
__device__ __forceinline__ float b2f(unsigned u) {
  return __builtin_bit_cast(float, u << 16);
}

__device__ __forceinline__ void gload16(const void* g, void* l) {
  __builtin_amdgcn_global_load_lds((const __attribute__((address_space(1))) void*)g,
                                   (__attribute__((address_space(3))) void*)l, 16, 0, 0);
}

__device__ __forceinline__ void barrier_mem() {
  asm volatile("s_barrier" ::: "memory");
}
template <int N>
__device__ __forceinline__ void waitn() {
  if constexpr (N == 0) asm volatile("s_waitcnt vmcnt(0)" ::: "memory");
  else if constexpr (N == 6) asm volatile("s_waitcnt vmcnt(6)" ::: "memory");
  else asm volatile("s_waitcnt vmcnt(8)" ::: "memory");
  __builtin_amdgcn_sched_barrier(0);
}

// ======================= universal bf16 MFMA GEMM =======================
// B-fragment n maps lane l15 -> LDS row (wc + l15*NF + n) so each lane's NF
// output columns are CONSECUTIVE -> vectorized (packed bf16) epilogue.
struct GemmP {
  const ushort_t* A; const ushort_t* B; const float* bias;
  ushort_t* Cb; const float* den;
  int nkt, lda, ldb, ldc;
  int aZrow, aZcol, bZrow, bZcol, cZrow;
  const ushort_t* A2; const ushort_t* B2;
  int nkt2, lda2, ldb2, a2Zrow, b2Zrow;
};

template <int TM, int TN, bool CONV>
__device__ __forceinline__ void mma_phase(const ushort_t* A, const ushort_t* B,
                                          int nkt, int lda, int ldb, int arow0,
                                          int acol0, int brow0, int bcol0,
                                          char* sm, int tid,
                                          f32x4 (&acc)[TM / 32][TN / 32]) {
  constexpr int MF = TM / 32, NF = TN / 32;
  constexpr int ABY = TM * 128, BBY = TN * 128, BUF = ABY + BBY;
  constexpr int RA = ABY / 4096, RB = BBY / 4096;
  const int lane = tid & 63, w = tid >> 6;
  const int wr = (w >> 1) * (TM / 2), wc = (w & 1) * (TN / 2);
  const int l15 = lane & 15, l4 = lane >> 4;

  auto stage = [&](int kt, int buf) {
    int ar0 = arow0, ac0 = acol0 + (kt << 6);
    if (CONV) {
      ar0 = arow0 + (kt >> 3);
      ac0 = acol0 + ((kt & 7) << 6);
    }
    char* s = sm + buf * BUF;
#pragma unroll
    for (int r = 0; r < RA; ++r) {
      const int f = (r << 12) + (tid << 4);
      const int row = f >> 7, sw = ((((f >> 4) & 7)) ^ (row & 7)) << 3;
      gload16(A + (size_t)(ar0 + row) * lda + ac0 + sw, s + f);
    }
    const int bc0 = bcol0 + (kt << 6);
#pragma unroll
    for (int r = 0; r < RB; ++r) {
      const int f = (r << 12) + (tid << 4);
      const int row = f >> 7, sw = ((((f >> 4) & 7)) ^ ((row >> 2) & 7)) << 3;
      gload16(B + (size_t)(brow0 + row) * ldb + bc0 + sw, s + ABY + f);
    }
  };

  stage(0, 0);
  int cur = 0;
  for (int kt = 0; kt < nkt; ++kt) {
    if (kt + 1 < nkt) {
      stage(kt + 1, cur ^ 1);  // prefetch next tile
      waitn<RA + RB>();        // wait ONLY the older (current) tile
    } else {
      waitn<0>();
    }
    barrier_mem();
    char* s = sm + cur * BUF;
#pragma unroll
    for (int kk = 0; kk < 2; ++kk) {
      short8 af[MF], bfv[NF];
#pragma unroll
      for (int m = 0; m < MF; ++m) {
        const int rt = wr + (m << 4) + l15;
        af[m] = *(const short8*)(s + rt * 128 +
                                 (((kk << 6) + (l4 << 4)) ^ ((rt & 7) << 4)));
      }
#pragma unroll
      for (int n = 0; n < NF; ++n) {
        const int rt = wc + l15 * NF + n;
        bfv[n] = *(const short8*)(s + ABY + rt * 128 +
                                  (((kk << 6) + (l4 << 4)) ^
                                   (((rt >> 2) & 7) << 4)));
      }
#pragma unroll
      for (int m = 0; m < MF; ++m)
#pragma unroll
        for (int n = 0; n < NF; ++n)
          acc[m][n] = __builtin_amdgcn_mfma_f32_16x16x32_bf16(af[m], bfv[n],
                                                              acc[m][n], 0, 0, 0);
    }
    __builtin_amdgcn_sched_barrier(0);
    asm volatile("s_waitcnt lgkmcnt(0)" ::: "memory");
    barrier_mem();
    cur ^= 1;
  }
}

// ACT: 0 none, 1 phi, 2 gelu, 3 phi-if-row<512 (fused k|v)
template <int TM, int TN, int ACT, bool READC, bool PADA, bool PADC,
          bool BIASROW, bool TRIMASK, bool SKIPUP, bool DIVDEN, bool TWOPH,
          bool CONV, bool HALFK>
__device__ __forceinline__ void gemm_body(const GemmP& p, int bm, int bn,
                                          int z, int tid, char* smem) {
  constexpr int MF = TM / 32, NF = TN / 32;
  const int lane = tid & 63, w = tid >> 6;
  const int wr = (w >> 1) * (TM / 2), wc = (w & 1) * (TN / 2);
  const int l15 = lane & 15, l4 = lane >> 4;
  const int cb = bn + wc + l15 * NF;  // lane's first output column

  if (SKIPUP && bn >= bm + TM) {  // fully-masked tile: zero-fill Cb
#pragma unroll
    for (int m = 0; m < MF; ++m)
#pragma unroll
      for (int j = 0; j < 4; ++j) {
        const int rloc = bm + wr + (m << 4) + (l4 << 2) + j;
        const size_t crow = (size_t)p.cZrow * z + rloc;
        if constexpr (NF == 4) {
          uint2 z4{0, 0};
          *(uint2*)&p.Cb[crow * p.ldc + cb] = z4;
        } else {
          *(unsigned*)&p.Cb[crow * p.ldc + cb] = 0;
        }
      }
    return;
  }

  f32x4 acc[MF][NF];
#pragma unroll
  for (int m = 0; m < MF; ++m)
#pragma unroll
    for (int n = 0; n < NF; ++n)
#pragma unroll
      for (int j = 0; j < 4; ++j) acc[m][n][j] = 0.f;

  int arow0 = bm + p.aZrow * z;
  if (PADA) arow0 = bm + ((bm >> 11) << 1);  // padded batch base
  int nkt1 = p.nkt;
  if (HALFK) nkt1 = min(p.nkt, (bm + TM) >> 6);  // causal K truncation
  mma_phase<TM, TN, CONV>(p.A, p.B, nkt1, p.lda, p.ldb, arow0, p.aZcol * z,
                          bn + p.bZrow * z, p.bZcol * z, smem, tid, acc);
  if (TWOPH)
    mma_phase<TM, TN, false>(p.A2, p.B2, p.nkt2, p.lda2, p.ldb2,
                             bm + p.a2Zrow * z, 0, bn + p.b2Zrow * z, 0, smem,
                             tid, acc);

  float bcol[NF];
  if (p.bias && !BIASROW) {
#pragma unroll
    for (int n = 0; n < NF; ++n) bcol[n] = p.bias[cb + n];
  }
  int crow_base = bm;
  if (PADC) crow_base = bm + ((bm >> 11) << 1) + 2;
#pragma unroll
  for (int m = 0; m < MF; ++m) {
#pragma unroll
    for (int j = 0; j < 4; ++j) {
      const int rloc = wr + (m << 4) + (l4 << 2) + j;
      const size_t crow = (size_t)p.cZrow * z + crow_base + rloc;
      float inv = 1.f;
      if (DIVDEN) inv = 1.f / (p.den[crow] + 1e-6f);
      float brbias = 0.f;
      if (BIASROW && p.bias) brbias = p.bias[bm + rloc];
      const size_t cidx0 = crow * p.ldc + cb;
      float oldv[NF];
      if (READC) {
        if constexpr (NF == 4) {
          const uint2 o = *(const uint2*)&p.Cb[cidx0];
          oldv[0] = b2f(o.x & 0xffffu); oldv[1] = b2f(o.x >> 16);
          oldv[2] = b2f(o.y & 0xffffu); oldv[3] = b2f(o.y >> 16);
        } else {
          const unsigned o = *(const unsigned*)&p.Cb[cidx0];
          oldv[0] = b2f(o & 0xffffu); oldv[1] = b2f(o >> 16);
        }
      }
      ushort_t uv[NF];
#pragma unroll
      for (int n = 0; n < NF; ++n) {
        float v = acc[m][n][j];
        if (p.bias) v += BIASROW ? brbias : bcol[n];
        if (ACT == 1) v = v > 0.f ? v + 1.f : __expf(v);
        if (ACT == 2) v = 0.5f * v * (1.f + erff(v * 0.70710678118654752f));
        if (ACT == 3 && (bm + rloc) < 512) v = v > 0.f ? v + 1.f : __expf(v);
        if (TRIMASK) {
          if (cb + n > bm + rloc) v = 0.f;
        }
        if (READC) v += oldv[n];
        if (DIVDEN) v *= inv;
        uv[n] = f2b(v);
      }
      if constexpr (NF == 4) {
        uint2 o;
        o.x = ((unsigned)uv[1] << 16) | uv[0];
        o.y = ((unsigned)uv[3] << 16) | uv[2];
        *(uint2*)&p.Cb[cidx0] = o;
      } else {
        *(unsigned*)&p.Cb[cidx0] = ((unsigned)uv[1] << 16) | uv[0];
      }
    }
  }
}

__device__ __forceinline__ void swz_decode(int r, int gx, int gy, int swz,
                                           int& bx, int& by) {
  if (swz) {
    const int per = gx * gy, cpx = per >> 3;
    const int s = (r & 7) * cpx + (r >> 3);
    if (gx >= gy) { bx = s / gy; by = s % gy; }
    else          { by = s / gx; bx = s % gx; }
  } else {
    bx = r % gx;
    by = r / gx;
  }
}

template <int TM, int TN, int ACT, bool READC, bool PADA, bool PADC,
          bool BIASROW, bool TRIMASK, bool SKIPUP, bool DIVDEN, bool TWOPH,
          bool CONV, bool SWZ, bool HALFK>
__global__ __launch_bounds__(256) void gemm_mfma(GemmP p) {
  __shared__ __align__(16) char smem[2 * (TM + TN) * 128];
  int bxx = blockIdx.x, byy = blockIdx.y;
  if (SWZ) {
    const int gx = gridDim.x, gy = gridDim.y;
    swz_decode(byy * gx + bxx, gx, gy, 1, bxx, byy);
  }
  gemm_body<TM, TN, ACT, READC, PADA, PADC, BIASROW, TRIMASK, SKIPUP, DIVDEN,
            TWOPH, CONV, HALFK>(p, bxx * TM, byy * TN, blockIdx.z, threadIdx.x,
                                smem);
}

// ======================= small phase bodies =======================

__device__ __forceinline__ void ksum_body(const ushort_t* __restrict__ kT,
                                          float* __restrict__ ks, int unit,
                                          int nunits, int tid) {
  const int wid = tid >> 6, lane = tid & 63;
  const int nw = nunits << 2;
  for (int it = (unit << 2) + wid; it < B_SZ * 7 * E_DIM; it += nw) {
    const int zi = it >> 9, e = it & 511;
    const int z = ((zi / 7) << 3) + zi % 7;
    const uint2 u =
        *(const uint2*)(kT + (size_t)e * ROWS + (z << 8) + (lane << 2));
    float s = b2f(u.x & 0xffffu) + b2f(u.x >> 16) + b2f(u.y & 0xffffu) +
              b2f(u.y >> 16);
#pragma unroll
    for (int off = 32; off; off >>= 1) s += __shfl_xor(s, off);
    if (lane == 0) ks[(z << 9) + e] = s;
  }
}

// ============ mega kernels: template-specialized multi-GEMM launches ========

// qk (128x128, ACT=phi, swz grid 64x8) || kvT (128x128, ACT=3, BIASROW, 8x64)
__global__ __launch_bounds__(256) void mega_qkv(GemmP pa, GemmP pb) {
  __shared__ __align__(16) char smem[65536];
  const int tid = threadIdx.x;
  const int bid = blockIdx.x;
  if (bid < 512) {
    int bx, by;
    swz_decode(bid, 64, 8, 1, bx, by);
    gemm_body<128, 128, 1, 0, 0, 0, 0, 0, 0, 0, 0, 0, 0>(pa, bx << 7, by << 7,
                                                          0, tid, smem);
  } else {
    int bx, by;
    swz_decode(bid - 512, 8, 64, 1, bx, by);
    gemm_body<128, 128, 3, 0, 0, 0, 1, 0, 0, 0, 0, 0, 0>(pb, bx << 7, by << 7,
                                                          0, tid, smem);
  }
}

// P (128x128, z in 28 chunks) || Sc (128x64, TRIMASK+SKIPUP) || ksum tail
__global__ __launch_bounds__(256) void mega_psck(GemmP pp, GemmP ps,
                                                 const ushort_t* kT,
                                                 float* ks) {
  __shared__ __align__(16) char smem[65536];
  const int tid = threadIdx.x;
  const int bid = blockIdx.x;
  if (bid < 448) {  // P-GEMM, chunk-7 skipped
    int z = bid >> 4;
    z = (z / 7) * 8 + z % 7;
    const int r = bid & 15;
    gemm_body<128, 128, 0, 0, 0, 0, 0, 0, 0, 0, 0, 0, 0>(
        pp, (r & 3) << 7, (r >> 2) << 7, z, tid, smem);
  } else if (bid < 704) {  // intra-chunk scores
    const int v = bid - 448;
    const int z = v >> 3, r = v & 7;
    gemm_body<128, 64, 0, 0, 0, 0, 0, 1, 1, 0, 0, 0, 0>(
        ps, (r & 1) << 7, (r >> 1) << 6, z, tid, smem);
  } else {
    ksum_body(kT, ks, bid - 704, 256, tid);
  }
}

// ======================= prep kernel (vectorized, + transpose tail) =========

struct CvtP {
  const float *in_W, *cc_W, *Wq, *Wk, *Wv, *Wo, *c1W, *c2W, *bq, *bk, *bv;
  ushort_t *winb, *wconv, *wqkb, *wkvb, *wob, *wc1, *wc2;
  float *bqk, *bkv;
  ushort_t* t2pad;
  const float* x; ushort_t* xT;
};

__device__ __forceinline__ void cvt8(const float* s, ushort_t* d) {
  const float4 a = *(const float4*)s;
  const float4 b = *(const float4*)(s + 4);
  uint4 o;
  o.x = ((unsigned)f2b(a.y) << 16) | f2b(a.x);
  o.y = ((unsigned)f2b(a.w) << 16) | f2b(a.z);
  o.z = ((unsigned)f2b(b.y) << 16) | f2b(b.x);
  o.w = ((unsigned)f2b(b.w) << 16) | f2b(b.z);
  *(uint4*)d = o;
}

#define NB_CVT 2048
__global__ __launch_bounds__(256) void cvt_all(CvtP c) {
  __shared__ float t[64][65];
  const int tid = threadIdx.x;
  if (blockIdx.x >= NB_CVT) {  // transpose_x tail: 128 blocks
    const int v = blockIdx.x - NB_CVT;  // 0..127
    const int b = v >> 5, s0 = (v & 31) << 6;
#pragma unroll
    for (int i = 0; i < 16; ++i) {
      int idx = tid + (i << 8);
      int ch = idx >> 6, s = idx & 63;
      t[ch][s] = c.x[(((size_t)(b * CIN_D + ch)) << 11) + s0 + s];
    }
    __syncthreads();
#pragma unroll
    for (int i = 0; i < 16; ++i) {
      int idx = tid + (i << 8);
      int s = idx >> 6, ch = idx & 63;
      c.xT[(((size_t)(b * S_LEN + s0 + s)) << 6) + ch] = f2b(t[ch][s]);
    }
    return;
  }
  // vectorized conversion: units of 8 elements; all section sizes are 8-aligned
  const size_t NU = (32768 + 786432 + 2097152 * 2 + 1048576 * 3 + 4096 * 2 +
                     4096) >> 3;
  for (size_t iu = (size_t)blockIdx.x * 256 + tid; iu < NU;
       iu += (size_t)NB_CVT * 256) {
    size_t j = iu << 3;
    if (j < 32768) { cvt8(c.in_W + j, c.winb + j); continue; }
    j -= 32768;
    if (j < 786432) {  // wconv[n][tap*512+k] = cc_W[n][k][tap], stride-3 gather
      size_t n = j / 1536, r = j % 1536;
      const float* src = c.cc_W + n * 1536 + (r & 511) * 3 + (r >> 9);
      float v[8];
#pragma unroll
      for (int tS = 0; tS < 8; ++tS) v[tS] = src[tS * 3];
      uint4 o;
      o.x = ((unsigned)f2b(v[1]) << 16) | f2b(v[0]);
      o.y = ((unsigned)f2b(v[3]) << 16) | f2b(v[2]);
      o.z = ((unsigned)f2b(v[5]) << 16) | f2b(v[4]);
      o.w = ((unsigned)f2b(v[7]) << 16) | f2b(v[6]);
      *(uint4*)(c.wconv + j) = o;
      continue;
    }
    j -= 786432;
    if (j < 2097152) {  // wqkb = [Wq;Wk]
      size_t l = j >> 19, r = j & 524287, row = r >> 9, k = r & 511;
      const float* src = row < 512
                             ? c.Wq + l * 262144 + row * 512 + k
                             : c.Wk + l * 262144 + (row - 512) * 512 + k;
      cvt8(src, c.wqkb + j);
      continue;
    }
    j -= 2097152;
    if (j < 2097152) {  // wkvb = [Wk;Wv]
      size_t l = j >> 19, r = j & 524287, row = r >> 9, k = r & 511;
      const float* src = row < 512
                             ? c.Wk + l * 262144 + row * 512 + k
                             : c.Wv + l * 262144 + (row - 512) * 512 + k;
      cvt8(src, c.wkvb + j);
      continue;
    }
    j -= 2097152;
    if (j < 1048576) { cvt8(c.Wo + j, c.wob + j); continue; }
    j -= 1048576;
    if (j < 1048576) { cvt8(c.c1W + j, c.wc1 + j); continue; }
    j -= 1048576;
    if (j < 1048576) { cvt8(c.c2W + j, c.wc2 + j); continue; }
    j -= 1048576;
    if (j < 4096) {  // bqk floats
      size_t l = j >> 10, r = j & 1023;
      const float* src = r < 512 ? c.bq + l * 512 + r : c.bk + l * 512 + r - 512;
      *(float4*)(c.bqk + j) = *(const float4*)src;
      *(float4*)(c.bqk + j + 4) = *(const float4*)(src + 4);
      continue;
    }
    j -= 4096;
    if (j < 4096) {  // bkv floats
      size_t l = j >> 10, r = j & 1023;
      const float* src = r < 512 ? c.bk + l * 512 + r : c.bv + l * 512 + r - 512;
      *(float4*)(c.bkv + j) = *(const float4*)src;
      *(float4*)(c.bkv + j + 4) = *(const float4*)(src + 4);
      continue;
    }
    j -= 4096;
    {  // zero-fill the 2 pad rows at each batch start of t2pad
      int b = (int)(j >> 10), r = (int)(j & 1023);
      uint4 z4{0, 0, 0, 0};
      *(uint4*)(c.t2pad + (size_t)(b * PADR) * E_DIM + r) = z4;
    }
  }
}

// wave-per-row layernorm over bf16 latent: 4 rows / block
__global__ __launch_bounds__(256) void layernorm_b(const ushort_t* __restrict__ x,
                                                   const float* __restrict__ g,
                                                   const float* __restrict__ bb,
                                                   ushort_t* __restrict__ y) {
  const int wid = threadIdx.x >> 6, lane = threadIdx.x & 63;
  const int row = (blockIdx.x << 2) + wid;
  const ushort_t* xr = x + ((size_t)row << 9);
  const uint4 u = *(const uint4*)(xr + (lane << 3));  // 8 bf16
  float v[8];
  v[0] = b2f(u.x & 0xffffu); v[1] = b2f(u.x >> 16);
  v[2] = b2f(u.y & 0xffffu); v[3] = b2f(u.y >> 16);
  v[4] = b2f(u.z & 0xffffu); v[5] = b2f(u.z >> 16);
  v[6] = b2f(u.w & 0xffffu); v[7] = b2f(u.w >> 16);
  float s = 0.f, q2 = 0.f;
#pragma unroll
  for (int i = 0; i < 8; ++i) { s += v[i]; q2 += v[i] * v[i]; }
#pragma unroll
  for (int off = 32; off; off >>= 1) {
    s += __shfl_xor(s, off);
    q2 += __shfl_xor(q2, off);
  }
  const float m = s * (1.f / 512.f);
  const float r = rsqrtf(q2 * (1.f / 512.f) - m * m + 1e-5f);
  const int c = lane << 3;
  const float4 g0 = *(const float4*)(g + c);
  const float4 g1 = *(const float4*)(g + c + 4);
  const float4 b0 = *(const float4*)(bb + c);
  const float4 b1 = *(const float4*)(bb + c + 4);
  uint4 o;
  o.x = ((unsigned)f2b((v[1] - m) * r * g0.y + b0.y) << 16) |
        f2b((v[0] - m) * r * g0.x + b0.x);
  o.y = ((unsigned)f2b((v[3] - m) * r * g0.w + b0.w) << 16) |
        f2b((v[2] - m) * r * g0.z + b0.z);
  o.z = ((unsigned)f2b((v[5] - m) * r * g1.y + b1.y) << 16) |
        f2b((v[4] - m) * r * g1.x + b1.x);
  o.w = ((unsigned)f2b((v[7] - m) * r * g1.w + b1.w) << 16) |
        f2b((v[6] - m) * r * g1.z + b1.z);
  *(uint4*)(y + ((size_t)row << 9) + c) = o;
}

// merged: blocks 0..2047 = exclusive chunk prefix Pb->PTb, 2 elems/thread
//         (packed bf16 loads/stores; chunk-7 Pb never computed -> skipped);
//         blocks 2048..4095 = den (wave per row, vectorized, ks prefix inline)
__global__ __launch_bounds__(256) void misc_k(
    const ushort_t* __restrict__ Pb, ushort_t* __restrict__ PTb,
    const ushort_t* __restrict__ Sc, const ushort_t* __restrict__ qk,
    const float* __restrict__ ksum, float* __restrict__ den) {
  int bid = blockIdx.x;
  if (bid < 2048) {
    const size_t idx = ((size_t)bid << 8) + threadIdx.x;  // < B*E*E/2
    const int b = (int)(idx >> 17);
    const size_t r = (idx & ((1u << 17) - 1)) << 1;  // even element index
    float a0 = 0.f, a1 = 0.f;
#pragma unroll
    for (int j = 0; j < NCHK; ++j) {
      const size_t o = (((size_t)(b * NCHK + j)) << 18) + r;
      *(unsigned*)&PTb[o] = ((unsigned)f2b(a1) << 16) | f2b(a0);
      if (j < NCHK - 1) {
        const unsigned u = *(const unsigned*)&Pb[o];
        a0 += b2f(u & 0xffffu);
        a1 += b2f(u >> 16);
      }
    }
  } else {
    bid -= 2048;
    const int wid = threadIdx.x >> 6, lane = threadIdx.x & 63;
    const int row = (bid << 2) + wid;  // < 8192
    const int z = row >> 8, sl = row & 255;
    const ushort_t* sr = Sc + (((size_t)z) << 16) + ((size_t)sl << 8);
    const uint2 s4 = *(const uint2*)(sr + (lane << 2));  // 4 bf16 of Sc row
    float s = b2f(s4.x & 0xffffu) + b2f(s4.x >> 16) + b2f(s4.y & 0xffffu) +
              b2f(s4.y >> 16);
    const ushort_t* qr = qk + (size_t)row * QLD;
    const int j0 = z & ~7;
#pragma unroll
    for (int it = 0; it < 2; ++it) {
      const int e = (lane << 2) + (it << 8);
      const uint2 q4 = *(const uint2*)(qr + e);
      float k0 = 0.f, k1 = 0.f, k2 = 0.f, k3 = 0.f;
      for (int j = j0; j < z; ++j) {
        const float4 kj = *(const float4*)(ksum + (j << 9) + e);
        k0 += kj.x; k1 += kj.y; k2 += kj.z; k3 += kj.w;
      }
      s += b2f(q4.x & 0xffffu) * k0 + b2f(q4.x >> 16) * k1 +
           b2f(q4.y & 0xffffu) * k2 + b2f(q4.y >> 16) * k3;
    }
#pragma unroll
    for (int off = 32; off; off >>= 1) s += __shfl_xor(s, off);
    if (lane == 0) den[row] = s;
  }
}

__global__ __launch_bounds__(256) void out_proj(const ushort_t* __restrict__ lat,
                                                const float* __restrict__ W,
                                                const float* __restrict__ bias,
                                                float* __restrict__ out) {
  const int b = blockIdx.z, bs = blockIdx.x << 6;
  const int tid = threadIdx.x, tm = tid >> 4, tn = tid & 15;
  const int lr = tid >> 2, lc = (tid & 3) << 2;
  __shared__ float As[16][64], Ws[16][64];
  float acc[4][4] = {{0.f}};
  for (int k0 = 0; k0 < E_DIM; k0 += 16) {
    const uint2 ra =
        *(const uint2*)(lat + (((size_t)(b * S_LEN + bs + lr)) << 9) + k0 + lc);
    As[lc + 0][lr] = b2f(ra.x & 0xffffu);
    As[lc + 1][lr] = b2f(ra.x >> 16);
    As[lc + 2][lr] = b2f(ra.y & 0xffffu);
    As[lc + 3][lr] = b2f(ra.y >> 16);
    float4 wv = *(const float4*)(W + (((size_t)lr) << 9) + k0 + lc);
    Ws[lc + 0][lr] = wv.x; Ws[lc + 1][lr] = wv.y;
    Ws[lc + 2][lr] = wv.z; Ws[lc + 3][lr] = wv.w;
    __syncthreads();
#pragma unroll
    for (int kk = 0; kk < 16; ++kk) {
      const float4 a4 = *(const float4*)&As[kk][tm << 2];
      const float4 b4 = *(const float4*)&Ws[kk][tn << 2];
      const float aa[4] = {a4.x, a4.y, a4.z, a4.w};
      const float bb[4] = {b4.x, b4.y, b4.z, b4.w};
#pragma unroll
      for (int i = 0; i < 4; ++i)
#pragma unroll
        for (int j2 = 0; j2 < 4; ++j2) acc[i][j2] += aa[i] * bb[j2];
    }
    __syncthreads();
  }
#pragma unroll
  for (int i = 0; i < 4; ++i)
#pragma unroll
    for (int j2 = 0; j2 < 4; ++j2) {
      const int o = (tn << 2) + j2, sl = bs + (tm << 2) + i;
      out[(((size_t)(b * COUT_D + o)) << 11) + sl] = acc[i][j2] + bias[o];
    }
}

// ======================= host launcher =======================
extern "C" void kernel_launch(void* const* d_in, const int* in_sizes, int n_in,
                              void* d_out, int out_size, void* d_ws,
                              size_t ws_size, hipStream_t stream) {
  const float* x = (const float*)d_in[0];
  const float* in_W = (const float*)d_in[1];
  const float* in_b = (const float*)d_in[2];
  const float* cc_W = (const float*)d_in[3];
  const float* cc_b = (const float*)d_in[4];
  const float* ln1g = (const float*)d_in[5];
  const float* ln1b = (const float*)d_in[6];
  const float* ln2g = (const float*)d_in[7];
  const float* ln2b = (const float*)d_in[8];
  const float* Wq = (const float*)d_in[9];
  const float* bq = (const float*)d_in[10];
  const float* Wk = (const float*)d_in[11];
  const float* bk = (const float*)d_in[12];
  const float* Wv = (const float*)d_in[13];
  const float* bv = (const float*)d_in[14];
  const float* Wo = (const float*)d_in[15];
  const float* bo = (const float*)d_in[16];
  const float* c1W = (const float*)d_in[17];
  const float* c1b = (const float*)d_in[18];
  const float* c2W = (const float*)d_in[19];
  const float* c2b = (const float*)d_in[20];
  const float* oW = (const float*)d_in[21];
  const float* ob = (const float*)d_in[22];
  float* out = (float*)d_out;

  const size_t NE = (size_t)ROWS * E_DIM;  // 4194304
  float* ks = (float*)d_ws;  // 16384
  float* den = ks + 16384;   // 8192
  float* bqk = den + 8192;   // 4096
  float* bkv = bqk + 4096;   // 4096
  ushort_t* u = (ushort_t*)(bkv + 4096);
  ushort_t* latb = u;   u += NE;
  ushort_t* Pb = u;     u += 8388608;
  ushort_t* xT = u;     u += (size_t)ROWS * CIN_D;
  ushort_t* t2pad = u;  u += (size_t)B_SZ * PADR * E_DIM;
  ushort_t* h = u;      u += NE;
  ushort_t* qk = u;     u += (size_t)ROWS * QLD;
  ushort_t* kvT = u;    u += (size_t)1024 * ROWS;
  ushort_t* PTb = u;    u += 8388608;
  ushort_t* t2b = u;    u += NE;
  ushort_t* winb = u;   u += 32768;
  ushort_t* wconv = u;  u += 786432;
  ushort_t* wqkb = u;   u += 2097152;
  ushort_t* wkvb = u;   u += 2097152;
  ushort_t* wob = u;    u += 1048576;
  ushort_t* wc1 = u;    u += 1048576;
  ushort_t* wc2 = u;    u += 1048576;
  ushort_t* Sc = t2pad;  // alias: t2pad dead after conv
  ushort_t* kT = kvT;
  ushort_t* vT = kvT + (size_t)512 * ROWS;

  const dim3 blk(256);

  CvtP cp{in_W, cc_W, Wq, Wk, Wv, Wo, c1W, c2W, bq, bk, bv,
          winb, wconv, wqkb, wkvb, wob, wc1, wc2, bqk, bkv, t2pad, x, xT};
  cvt_all<<<dim3(NB_CVT + 128), blk, 0, stream>>>(cp);

  GemmP p;
  auto clr = [&]() {
    p = GemmP{};
    p.lda = E_DIM; p.ldb = E_DIM; p.ldc = E_DIM;
  };

  // template args: TM,TN,ACT,READC,PADA,PADC,BIASROW,TRIMASK,SKIPUP,DIVDEN,
  //                TWOPH,CONV,SWZ,HALFK
  // input projection -> padded bf16 latent (K=64); 512 blocks = 2/CU
  clr(); p.A = xT; p.B = winb; p.bias = in_b; p.Cb = t2pad;
  p.nkt = 1; p.lda = 64; p.ldb = 64;
  gemm_mfma<128,64,0,0,0,1,0,0,0,0,0,0,1,0><<<dim3(64,8), blk, 0, stream>>>(p);
  // fused causal conv: one GEMM, K=1536 (3 taps x 512) -> latb; 512 blocks
  clr(); p.A = t2pad; p.B = wconv; p.bias = cc_b; p.Cb = latb;
  p.nkt = 24; p.ldb = 1536;
  gemm_mfma<128,64,0,0,1,0,0,0,0,0,0,1,1,0><<<dim3(64,8), blk, 0, stream>>>(p);

  for (int i = 0; i < L_NUM; ++i) {
    const size_t wOff = (size_t)i * E_DIM * E_DIM;
    const size_t bOff = (size_t)i * E_DIM;
    layernorm_b<<<dim3(ROWS / 4), blk, 0, stream>>>(latb, ln1g + bOff,
                                                    ln1b + bOff, h);
    // MEGA: fused q|k GEMM || fused kT|vT GEMM (template-specialized)
    GemmP pa{}; pa.lda = E_DIM; pa.ldb = E_DIM;
    pa.A = h; pa.B = wqkb + (size_t)i * 524288; pa.bias = bqk + i * 1024;
    pa.Cb = qk; pa.nkt = 8; pa.ldc = QLD;
    GemmP pb{}; pb.lda = E_DIM; pb.ldb = E_DIM;
    pb.A = wkvb + (size_t)i * 524288; pb.B = h; pb.bias = bkv + i * 1024;
    pb.Cb = kvT; pb.nkt = 8; pb.ldc = ROWS;
    mega_qkv<<<dim3(1024), blk, 0, stream>>>(pa, pb);
    // MEGA: chunk-KV P (chunk-7 skipped) || intra-chunk Sc || ksum tail
    GemmP pp{};
    pp.A = vT; pp.B = kT; pp.Cb = Pb; pp.nkt = 4;
    pp.lda = ROWS; pp.ldb = ROWS; pp.ldc = E_DIM;
    pp.aZcol = CHK; pp.bZcol = CHK; pp.cZrow = E_DIM;
    GemmP ps{};
    ps.A = qk; ps.B = qk + 512; ps.Cb = Sc; ps.nkt = 8;
    ps.lda = QLD; ps.ldb = QLD; ps.ldc = CHK;
    ps.aZrow = CHK; ps.bZrow = CHK; ps.cZrow = CHK;
    mega_psck<<<dim3(960), blk, 0, stream>>>(pp, ps, kT, ks);
    // merged: prefix (Pb->PTb, packed) || den (vectorized)
    misc_k<<<dim3(4096), blk, 0, stream>>>(Pb, PTb, Sc, qk, ks, den);
    // combine: (Sc@vT + q@PTb) / den -> t2b (bf16); causal K-trunc on Sc phase
    clr(); p.A = Sc; p.B = vT; p.Cb = t2b; p.den = den;
    p.nkt = 4; p.lda = CHK; p.ldb = ROWS; p.aZrow = CHK; p.bZcol = CHK;
    p.cZrow = CHK;
    p.A2 = qk; p.B2 = PTb; p.nkt2 = 8; p.lda2 = QLD; p.ldb2 = E_DIM;
    p.a2Zrow = CHK; p.b2Zrow = E_DIM;
    gemm_mfma<64,128,0,0,0,0,0,0,0,1,1,0,0,1><<<dim3(4,4,B_SZ*NCHK), blk, 0, stream>>>(p);
    // latb += t2b @ Wo^T  (bf16 residual RMW)
    clr(); p.A = t2b; p.B = wob + wOff; p.bias = bo + bOff; p.Cb = latb;
    p.nkt = 8;
    gemm_mfma<64,128,0,1,0,0,0,0,0,0,0,0,1,0><<<dim3(128,4), blk, 0, stream>>>(p);
    layernorm_b<<<dim3(ROWS / 4), blk, 0, stream>>>(latb, ln2g + bOff,
                                                    ln2b + bOff, h);
    // c1 (gelu) -> t2b ; latb += t2b @ c2^T
    clr(); p.A = h; p.B = wc1 + wOff; p.bias = c1b + bOff; p.Cb = t2b;
    p.nkt = 8;
    gemm_mfma<64,128,2,0,0,0,0,0,0,0,0,0,1,0><<<dim3(128,4), blk, 0, stream>>>(p);
    clr(); p.A = t2b; p.B = wc2 + wOff; p.bias = c2b + bOff; p.Cb = latb;
    p.nkt = 8;
    gemm_mfma<64,128,0,1,0,0,0,0,0,0,0,0,1,0><<<dim3(128,4), blk, 0, stream>>>(p);
  }
  out_proj<<<dim3(S_LEN / 64, 1, B_SZ), blk, 0, stream>>>(latb, oW, ob, out);
}